// Round 1
// baseline (642.519 us; speedup 1.0000x reference)
//
#include <hip/hip_runtime.h>

#define BB 48
#define NN 256
#define EE 1024
#define DD 256
#define CIN 256

__device__ __forceinline__ float lrelu(float t) { return t >= 0.0f ? t : 0.2f * t; }

// deg[e] = sum_n inc[n,e]; store 1/deg
__global__ __launch_bounds__(256) void k_deg(const float* __restrict__ inc, float* __restrict__ invdeg) {
  int e = blockIdx.x * 256 + threadIdx.x;
  float s = 0.f;
  for (int n = 0; n < NN; ++n) s += inc[(size_t)n * EE + e];
  invdeg[e] = 1.0f / s;
}

// incT[e,n] = inc[n,e]
__global__ __launch_bounds__(256) void k_incT(const float* __restrict__ inc, float* __restrict__ incT) {
  int idx = blockIdx.x * 256 + threadIdx.x;  // over N*E
  int n = idx / EE, e = idx % EE;
  incT[(size_t)e * NN + n] = inc[idx];
}

// h[b,n,d] = sum_c x_in[b,c,n]*W[c,d] + bias[n]   (bias indexed by node! N==D)
__global__ __launch_bounds__(256) void k_h(const float* __restrict__ x, const float* __restrict__ m,
                                           const float* __restrict__ hid, const float* __restrict__ W,
                                           const float* __restrict__ bias, float* __restrict__ h) {
  __shared__ float sa[16][68];
  __shared__ float sb[16][68];
  int b = blockIdx.z;
  int j0 = blockIdx.x * 64;  // d
  int i0 = blockIdx.y * 64;  // n
  int t = threadIdx.x;
  int tx = t & 15, ty = t >> 4;
  float acc[4][4] = {};
  for (int kk = 0; kk < CIN; kk += 16) {
    for (int r = 0; r < 4; ++r) {
      int idx = t + r * 256;
      int k = idx >> 6, i = idx & 63;
      int c = kk + k;
      const float* row;
      if (c < 96) row = x + ((size_t)b * 96 + c) * NN;
      else if (c < 192) row = m + ((size_t)b * 96 + (c - 96)) * NN;
      else row = hid + ((size_t)b * 64 + (c - 192)) * NN;
      sa[k][i] = row[i0 + i];
      sb[k][i] = W[(size_t)c * DD + j0 + i];
    }
    __syncthreads();
#pragma unroll
    for (int k = 0; k < 16; ++k) {
      float4 av = *(const float4*)&sa[k][ty * 4];
      float4 bv = *(const float4*)&sb[k][tx * 4];
      float ar[4] = {av.x, av.y, av.z, av.w};
      float br[4] = {bv.x, bv.y, bv.z, bv.w};
#pragma unroll
      for (int ii = 0; ii < 4; ++ii)
#pragma unroll
        for (int jj = 0; jj < 4; ++jj) acc[ii][jj] += ar[ii] * br[jj];
    }
    __syncthreads();
  }
  for (int ii = 0; ii < 4; ++ii) {
    int i = i0 + ty * 4 + ii;  // n
    float bv = bias[i];
    float4 v = make_float4(acc[ii][0] + bv, acc[ii][1] + bv, acc[ii][2] + bv, acc[ii][3] + bv);
    *(float4*)&h[((size_t)b * NN + i) * DD + j0 + tx * 4] = v;
  }
}

// edge1[b,d,e] = (sum_n h[b,n,d]*inc[n,e]) / deg[e]
__global__ __launch_bounds__(256) void k_edge1(const float* __restrict__ h, const float* __restrict__ inc,
                                               const float* __restrict__ invdeg, float* __restrict__ edge1) {
  __shared__ float sa[16][132];
  __shared__ float sb[16][132];
  int b = blockIdx.z;
  int j0 = blockIdx.x * 128;  // e
  int i0 = blockIdx.y * 128;  // d
  int t = threadIdx.x;
  int tx = t & 15, ty = t >> 4;
  const float* hb = h + (size_t)b * NN * DD;
  float acc[2][2][4][4] = {};
  for (int kk = 0; kk < NN; kk += 16) {
#pragma unroll
    for (int r = 0; r < 8; ++r) {
      int idx = t + r * 256;
      int k = idx >> 7, i = idx & 127;
      sa[k][i] = hb[(size_t)(kk + k) * DD + i0 + i];
      sb[k][i] = inc[(size_t)(kk + k) * EE + j0 + i];
    }
    __syncthreads();
#pragma unroll
    for (int k = 0; k < 16; ++k) {
      float4 a0 = *(const float4*)&sa[k][ty * 4];
      float4 a1 = *(const float4*)&sa[k][64 + ty * 4];
      float4 b0 = *(const float4*)&sb[k][tx * 4];
      float4 b1 = *(const float4*)&sb[k][64 + tx * 4];
      float ar[2][4] = {{a0.x, a0.y, a0.z, a0.w}, {a1.x, a1.y, a1.z, a1.w}};
      float br[2][4] = {{b0.x, b0.y, b0.z, b0.w}, {b1.x, b1.y, b1.z, b1.w}};
#pragma unroll
      for (int bi = 0; bi < 2; ++bi)
#pragma unroll
        for (int bj = 0; bj < 2; ++bj)
#pragma unroll
          for (int ii = 0; ii < 4; ++ii)
#pragma unroll
            for (int jj = 0; jj < 4; ++jj) acc[bi][bj][ii][jj] += ar[bi][ii] * br[bj][jj];
    }
    __syncthreads();
  }
  float* ob = edge1 + (size_t)b * DD * EE;
  for (int bi = 0; bi < 2; ++bi)
    for (int ii = 0; ii < 4; ++ii) {
      int i = i0 + bi * 64 + ty * 4 + ii;  // d
      for (int bj = 0; bj < 2; ++bj) {
        int j = j0 + bj * 64 + tx * 4;  // e
        float4 v = make_float4(acc[bi][bj][ii][0] * invdeg[j], acc[bi][bj][ii][1] * invdeg[j + 1],
                               acc[bi][bj][ii][2] * invdeg[j + 2], acc[bi][bj][ii][3] * invdeg[j + 3]);
        *(float4*)&ob[(size_t)i * EE + j] = v;
      }
    }
}

// out1[b,e,d] = sum_f edge1[b,d,f]*W2[f,e]
__global__ __launch_bounds__(256) void k_out1(const float* __restrict__ edge1, const float* __restrict__ W2,
                                              float* __restrict__ out1) {
  __shared__ float sa[16][132];
  __shared__ float sb[16][132];
  int b = blockIdx.z;
  int j0 = blockIdx.x * 128;  // d
  int i0 = blockIdx.y * 128;  // e
  int t = threadIdx.x;
  int tx = t & 15, ty = t >> 4;
  const float* eb = edge1 + (size_t)b * DD * EE;
  float acc[2][2][4][4] = {};
  for (int kk = 0; kk < EE; kk += 16) {
#pragma unroll
    for (int r = 0; r < 8; ++r) {
      int idx = t + r * 256;
      int k = idx >> 7, i = idx & 127;
      sa[k][i] = W2[(size_t)(kk + k) * EE + i0 + i];
    }
#pragma unroll
    for (int r = 0; r < 2; ++r) {
      int u = t + r * 256;
      int j = u >> 2, kq = (u & 3) * 4;
      float4 bv = *(const float4*)&eb[(size_t)(j0 + j) * EE + kk + kq];
      sb[kq + 0][j] = bv.x;
      sb[kq + 1][j] = bv.y;
      sb[kq + 2][j] = bv.z;
      sb[kq + 3][j] = bv.w;
    }
    __syncthreads();
#pragma unroll
    for (int k = 0; k < 16; ++k) {
      float4 a0 = *(const float4*)&sa[k][ty * 4];
      float4 a1 = *(const float4*)&sa[k][64 + ty * 4];
      float4 b0 = *(const float4*)&sb[k][tx * 4];
      float4 b1 = *(const float4*)&sb[k][64 + tx * 4];
      float ar[2][4] = {{a0.x, a0.y, a0.z, a0.w}, {a1.x, a1.y, a1.z, a1.w}};
      float br[2][4] = {{b0.x, b0.y, b0.z, b0.w}, {b1.x, b1.y, b1.z, b1.w}};
#pragma unroll
      for (int bi = 0; bi < 2; ++bi)
#pragma unroll
        for (int bj = 0; bj < 2; ++bj)
#pragma unroll
          for (int ii = 0; ii < 4; ++ii)
#pragma unroll
            for (int jj = 0; jj < 4; ++jj) acc[bi][bj][ii][jj] += ar[bi][ii] * br[bj][jj];
    }
    __syncthreads();
  }
  float* ob = out1 + (size_t)b * EE * DD;
  for (int bi = 0; bi < 2; ++bi)
    for (int ii = 0; ii < 4; ++ii) {
      int i = i0 + bi * 64 + ty * 4 + ii;  // e
      for (int bj = 0; bj < 2; ++bj) {
        int j = j0 + bj * 64 + tx * 4;  // d
        float4 v = make_float4(acc[bi][bj][ii][0], acc[bi][bj][ii][1], acc[bi][bj][ii][2], acc[bi][bj][ii][3]);
        *(float4*)&ob[(size_t)i * DD + j] = v;
      }
    }
}

// node_sc[b,n] = sum_d h[b,n,d]*a[d]
__global__ __launch_bounds__(256) void k_d1(const float* __restrict__ h, const float* __restrict__ a,
                                            float* __restrict__ node_sc) {
  int t = threadIdx.x;
  int w = t >> 6, l = t & 63;
  int row = blockIdx.x * 4 + w;  // b*N+n
  float4 hv = *(const float4*)&h[(size_t)row * DD + l * 4];
  float4 av = *(const float4*)&a[l * 4];
  float s = hv.x * av.x + hv.y * av.y + hv.z * av.z + hv.w * av.w;
#pragma unroll
  for (int off = 32; off > 0; off >>= 1) s += __shfl_down(s, off);
  if (l == 0) node_sc[row] = s;
}

// edge_sc[b,e] = sum_d out1[b,e,d]*a[D+d];  time_e[b,e] = lrelu(sum_d out1*a2[d] + pri_e*a2[D])
__global__ __launch_bounds__(256) void k_d2(const float* __restrict__ out1, const float* __restrict__ a,
                                            const float* __restrict__ a2, const float* __restrict__ pri_e,
                                            float* __restrict__ edge_sc, float* __restrict__ time_e) {
  int t = threadIdx.x;
  int w = t >> 6, l = t & 63;
  int row = blockIdx.x * 4 + w;  // b*E+e
  float4 v = *(const float4*)&out1[(size_t)row * DD + l * 4];
  float4 av = *(const float4*)&a[DD + l * 4];
  float4 a2v = *(const float4*)&a2[l * 4];
  float s1 = v.x * av.x + v.y * av.y + v.z * av.z + v.w * av.w;
  float s2 = v.x * a2v.x + v.y * a2v.y + v.z * a2v.z + v.w * a2v.w;
#pragma unroll
  for (int off = 32; off > 0; off >>= 1) {
    s1 += __shfl_down(s1, off);
    s2 += __shfl_down(s2, off);
  }
  if (l == 0) {
    edge_sc[row] = s1;
    time_e[row] = lrelu(s2 + pri_e[row] * a2[DD]);
  }
}

// softmax stats over n per (b,e)
__global__ __launch_bounds__(256) void k_d3(const float* __restrict__ incT, const float* __restrict__ node_sc,
                                            const float* __restrict__ edge_sc, const float* __restrict__ time_e,
                                            const float* __restrict__ a3, float* __restrict__ rmax,
                                            float* __restrict__ rinv) {
  int t = threadIdx.x;
  int w = t >> 6, l = t & 63;
  int row = blockIdx.x * 4 + w;  // b*E + e
  int b = row >> 10;
  int e = row & (EE - 1);
  float a30 = a3[0], a31 = a3[1];
  float esc = edge_sc[row], te = time_e[row];
  float s2v[4];
  bool msk[4];
  float vmax = -3.0e38f;
#pragma unroll
  for (int q = 0; q < 4; ++q) {
    int n = l + q * 64;
    float ic = incT[(size_t)e * NN + n];
    float s1 = lrelu(node_sc[(size_t)b * NN + n] + esc);
    float s2 = lrelu(te * a30 + s1 * a31);
    msk[q] = ic > 0.f;
    s2v[q] = s2;
    if (msk[q]) vmax = fmaxf(vmax, s2);
  }
#pragma unroll
  for (int off = 32; off > 0; off >>= 1) vmax = fmaxf(vmax, __shfl_xor(vmax, off));
  float ss = 0.f;
#pragma unroll
  for (int q = 0; q < 4; ++q)
    if (msk[q]) ss += __expf(s2v[q] - vmax);
#pragma unroll
  for (int off = 32; off > 0; off >>= 1) ss += __shfl_xor(ss, off);
  if (l == 0) {
    rmax[row] = vmax;
    rinv[row] = 1.0f / ss;
  }
}

// out0[b,d,n] = sum_e att_node[b,n,e]*out1[b,e,d]   (att computed on the fly)
__global__ __launch_bounds__(256) void k_f(const float* __restrict__ out1, const float* __restrict__ incT,
                                           const float* __restrict__ node_sc, const float* __restrict__ edge_sc,
                                           const float* __restrict__ time_e, const float* __restrict__ rmax,
                                           const float* __restrict__ rinv, const float* __restrict__ a3,
                                           float* __restrict__ out0) {
  __shared__ float sa[16][68];
  __shared__ float sb[16][68];
  int b = blockIdx.z;
  int j0 = blockIdx.x * 64;  // n
  int i0 = blockIdx.y * 64;  // d
  int t = threadIdx.x;
  int tx = t & 15, ty = t >> 4;
  float a30 = a3[0], a31 = a3[1];
  const float* vb = out1 + (size_t)b * EE * DD;
  float acc[4][4] = {};
  for (int kk = 0; kk < EE; kk += 16) {
#pragma unroll
    for (int r = 0; r < 4; ++r) {
      int idx = t + r * 256;
      int k = idx >> 6, i = idx & 63;  // k: e-offset; i: d-offset / n-offset
      sa[k][i] = vb[(size_t)(kk + k) * DD + i0 + i];
      int e = kk + k;
      int row = (b << 10) + e;
      float ic = incT[(size_t)e * NN + j0 + i];
      float c = 0.f;
      if (ic > 0.f) {
        float s1 = lrelu(node_sc[(size_t)b * NN + j0 + i] + edge_sc[row]);
        float s2 = lrelu(time_e[row] * a30 + s1 * a31);
        c = __expf(s2 - rmax[row]) * rinv[row];
      }
      sb[k][i] = c;
    }
    __syncthreads();
#pragma unroll
    for (int k = 0; k < 16; ++k) {
      float4 av = *(const float4*)&sa[k][ty * 4];
      float4 bv = *(const float4*)&sb[k][tx * 4];
      float ar[4] = {av.x, av.y, av.z, av.w};
      float br[4] = {bv.x, bv.y, bv.z, bv.w};
#pragma unroll
      for (int ii = 0; ii < 4; ++ii)
#pragma unroll
        for (int jj = 0; jj < 4; ++jj) acc[ii][jj] += ar[ii] * br[jj];
    }
    __syncthreads();
  }
  float* ob = out0 + (size_t)b * DD * NN;
  for (int ii = 0; ii < 4; ++ii) {
    int i = i0 + ty * 4 + ii;  // d
    *(float4*)&ob[(size_t)i * NN + j0 + tx * 4] =
        make_float4(acc[ii][0], acc[ii][1], acc[ii][2], acc[ii][3]);
  }
}

extern "C" void kernel_launch(void* const* d_in, const int* in_sizes, int n_in, void* d_out, int out_size,
                              void* d_ws, size_t ws_size, hipStream_t stream) {
  (void)in_sizes;
  (void)n_in;
  (void)out_size;
  (void)ws_size;
  const float* x = (const float*)d_in[0];
  const float* m = (const float*)d_in[1];
  const float* hid = (const float*)d_in[2];
  const float* pri_e = (const float*)d_in[3];
  const float* inc = (const float*)d_in[5];
  const float* W = (const float*)d_in[6];
  const float* bias = (const float*)d_in[7];
  const float* W2 = (const float*)d_in[8];
  const float* a = (const float*)d_in[9];
  const float* a2 = (const float*)d_in[10];
  const float* a3 = (const float*)d_in[11];

  float* out = (float*)d_out;
  float* out0 = out;                         // [B,D,N]; doubles as h scratch [B,N,D]
  float* out1 = out + (size_t)BB * DD * NN;  // [B,E,D]

  float* ws = (float*)d_ws;
  float* edge1 = ws;                           // B*D*E
  float* incT = edge1 + (size_t)BB * DD * EE;  // E*N
  float* invdeg = incT + (size_t)EE * NN;      // E
  float* node_sc = invdeg + EE;                // B*N
  float* edge_sc = node_sc + (size_t)BB * NN;  // B*E
  float* time_e = edge_sc + (size_t)BB * EE;   // B*E
  float* rmax = time_e + (size_t)BB * EE;      // B*E
  float* rinv = rmax + (size_t)BB * EE;        // B*E

  float* h = out0;  // h lives in out0 region until k_f overwrites it

  k_deg<<<dim3(EE / 256), 256, 0, stream>>>(inc, invdeg);
  k_incT<<<dim3((NN * EE) / 256), 256, 0, stream>>>(inc, incT);
  k_h<<<dim3(DD / 64, NN / 64, BB), 256, 0, stream>>>(x, m, hid, W, bias, h);
  k_edge1<<<dim3(EE / 128, DD / 128, BB), 256, 0, stream>>>(h, inc, invdeg, edge1);
  k_out1<<<dim3(DD / 128, EE / 128, BB), 256, 0, stream>>>(edge1, W2, out1);
  k_d1<<<dim3((BB * NN) / 4), 256, 0, stream>>>(h, a, node_sc);
  k_d2<<<dim3((BB * EE) / 4), 256, 0, stream>>>(out1, a, a2, pri_e, edge_sc, time_e);
  k_d3<<<dim3((BB * EE) / 4), 256, 0, stream>>>(incT, node_sc, edge_sc, time_e, a3, rmax, rinv);
  k_f<<<dim3(NN / 64, DD / 64, BB), 256, 0, stream>>>(out1, incT, node_sc, edge_sc, time_e, rmax, rinv, a3, out0);
}

// Round 2
// 425.732 us; speedup vs baseline: 1.5092x; 1.5092x over previous
//
#include <hip/hip_runtime.h>

#define BB 48
#define NN 256
#define EE 1024
#define DD 256
#define CIN 256

typedef __attribute__((ext_vector_type(4))) float f32x4;
typedef __attribute__((ext_vector_type(8))) _Float16 f16x8;
typedef __attribute__((ext_vector_type(4))) _Float16 f16x4;

__device__ __forceinline__ float lrelu(float t) { return t >= 0.0f ? t : 0.2f * t; }

__device__ __forceinline__ void gload16(const void* g, void* l) {
  __builtin_amdgcn_global_load_lds((const __attribute__((address_space(1))) void*)g,
                                   (__attribute__((address_space(3))) void*)l, 16, 0, 0);
}

// deg[e] = sum_n inc[n,e]; store 1/deg
__global__ __launch_bounds__(256) void k_deg(const float* __restrict__ inc, float* __restrict__ invdeg) {
  int e = blockIdx.x * 256 + threadIdx.x;
  float s = 0.f;
  for (int n = 0; n < NN; ++n) s += inc[(size_t)n * EE + e];
  invdeg[e] = 1.0f / s;
}

// incT[e,n] = inc[n,e]  (fp16, exact 0/1), LDS-tiled transpose
__global__ __launch_bounds__(256) void k_incT(const float* __restrict__ inc, _Float16* __restrict__ incT) {
  __shared__ float tile[64][65];
  int e0 = blockIdx.x * 64, n0 = blockIdx.y * 64;
  int t = threadIdx.x, c = t & 63, r = t >> 6;
#pragma unroll
  for (int i = 0; i < 16; ++i) tile[r + i * 4][c] = inc[(size_t)(n0 + r + i * 4) * EE + e0 + c];
  __syncthreads();
#pragma unroll
  for (int i = 0; i < 16; ++i) {
    int row = r + i * 4;
    incT[(size_t)(e0 + row) * NN + n0 + c] = (_Float16)tile[c][row];
  }
}

// W2T hi/lo fp16: w2t[e,f] = W2[f,e]
__global__ __launch_bounds__(256) void k_w2t(const float* __restrict__ W2, _Float16* __restrict__ hi,
                                             _Float16* __restrict__ lo) {
  __shared__ float tile[64][65];
  int f0 = blockIdx.x * 64, e0 = blockIdx.y * 64;
  int t = threadIdx.x, c = t & 63, r = t >> 6;
#pragma unroll
  for (int i = 0; i < 16; ++i) tile[r + i * 4][c] = W2[(size_t)(f0 + r + i * 4) * EE + e0 + c];
  __syncthreads();
#pragma unroll
  for (int i = 0; i < 16; ++i) {
    int row = r + i * 4;
    float v = tile[c][row];  // W2[f0+c][e0+row]
    _Float16 hh = (_Float16)v;
    hi[(size_t)(e0 + row) * EE + f0 + c] = hh;
    lo[(size_t)(e0 + row) * EE + f0 + c] = (_Float16)(v - (float)hh);
  }
}

// h[b,n,d] = sum_c x_in[b,c,n]*W[c,d] + bias[n]; also hT hi/lo fp16 [b,d,n]
__global__ __launch_bounds__(256) void k_h(const float* __restrict__ x, const float* __restrict__ m,
                                           const float* __restrict__ hid, const float* __restrict__ W,
                                           const float* __restrict__ bias, float* __restrict__ h,
                                           _Float16* __restrict__ hThi, _Float16* __restrict__ hTlo) {
  __shared__ float sa[16][68];
  __shared__ float sb[16][68];
  int b = blockIdx.z;
  int j0 = blockIdx.x * 64;  // d
  int i0 = blockIdx.y * 64;  // n
  int t = threadIdx.x;
  int tx = t & 15, ty = t >> 4;
  float acc[4][4] = {};
  for (int kk = 0; kk < CIN; kk += 16) {
    for (int r = 0; r < 4; ++r) {
      int idx = t + r * 256;
      int k = idx >> 6, i = idx & 63;
      int c = kk + k;
      const float* row;
      if (c < 96) row = x + ((size_t)b * 96 + c) * NN;
      else if (c < 192) row = m + ((size_t)b * 96 + (c - 96)) * NN;
      else row = hid + ((size_t)b * 64 + (c - 192)) * NN;
      sa[k][i] = row[i0 + i];
      sb[k][i] = W[(size_t)c * DD + j0 + i];
    }
    __syncthreads();
#pragma unroll
    for (int k = 0; k < 16; ++k) {
      float4 av = *(const float4*)&sa[k][ty * 4];
      float4 bv = *(const float4*)&sb[k][tx * 4];
      float ar[4] = {av.x, av.y, av.z, av.w};
      float br[4] = {bv.x, bv.y, bv.z, bv.w};
#pragma unroll
      for (int ii = 0; ii < 4; ++ii)
#pragma unroll
        for (int jj = 0; jj < 4; ++jj) acc[ii][jj] += ar[ii] * br[jj];
    }
    __syncthreads();
  }
  for (int ii = 0; ii < 4; ++ii) {
    int i = i0 + ty * 4 + ii;  // n
    float bv = bias[i];
    float4 v = make_float4(acc[ii][0] + bv, acc[ii][1] + bv, acc[ii][2] + bv, acc[ii][3] + bv);
    *(float4*)&h[((size_t)b * NN + i) * DD + j0 + tx * 4] = v;
  }
  _Float16* thb = hThi + (size_t)b * DD * NN;
  _Float16* tlb = hTlo + (size_t)b * DD * NN;
#pragma unroll
  for (int jj = 0; jj < 4; ++jj) {
    int d = j0 + tx * 4 + jj;
    f16x4 vh, vl;
#pragma unroll
    for (int ii = 0; ii < 4; ++ii) {
      float v = acc[ii][jj] + bias[i0 + ty * 4 + ii];
      _Float16 hh = (_Float16)v;
      vh[ii] = hh;
      vl[ii] = (_Float16)(v - (float)hh);
    }
    *(f16x4*)&thb[(size_t)d * NN + i0 + ty * 4] = vh;
    *(f16x4*)&tlb[(size_t)d * NN + i0 + ty * 4] = vl;
  }
}

// edge1[b,d,e] = (sum_n hT[d,n]*incT[e,n]) * invdeg[e]; 2-term MFMA, store hi/lo fp16
__global__ __launch_bounds__(256) void k_edge1(const _Float16* __restrict__ incT, const _Float16* __restrict__ hThi,
                                               const _Float16* __restrict__ hTlo, const float* __restrict__ invdeg,
                                               _Float16* __restrict__ e1hi, _Float16* __restrict__ e1lo) {
  __shared__ _Float16 smA[128 * 32];
  __shared__ _Float16 smBh[128 * 32];
  __shared__ _Float16 smBl[128 * 32];
  int b = blockIdx.z;
  int m0 = blockIdx.x * 128;  // e
  int n0 = blockIdx.y * 128;  // d
  int t = threadIdx.x, w = t >> 6, l = t & 63;
  int wm = w >> 1, wn = w & 1;
  int lr = l & 15, lq = (l >> 4) * 8;
  int rA = l >> 2, cA = (l & 3) * 8;
  const _Float16* Bh = hThi + (size_t)b * DD * NN;
  const _Float16* Bl = hTlo + (size_t)b * DD * NN;
  f32x4 acc[4][4];
  f32x4 z = {0.f, 0.f, 0.f, 0.f};
#pragma unroll
  for (int i = 0; i < 4; ++i)
#pragma unroll
    for (int j = 0; j < 4; ++j) acc[i][j] = z;
  for (int kk = 0; kk < NN; kk += 32) {
#pragma unroll
    for (int q = 0; q < 2; ++q) {
      int rr = (q * 4 + w) * 16 + rA;
      int lb = (q * 4 + w) * 512;
      gload16(incT + (size_t)(m0 + rr) * NN + kk + cA, smA + lb);
      gload16(Bh + (size_t)(n0 + rr) * NN + kk + cA, smBh + lb);
      gload16(Bl + (size_t)(n0 + rr) * NN + kk + cA, smBl + lb);
    }
    __syncthreads();
    f16x8 af[4], fh[4], fl[4];
#pragma unroll
    for (int i = 0; i < 4; ++i) {
      af[i] = *(const f16x8*)&smA[(wm * 64 + i * 16 + lr) * 32 + lq];
      fh[i] = *(const f16x8*)&smBh[(wn * 64 + i * 16 + lr) * 32 + lq];
      fl[i] = *(const f16x8*)&smBl[(wn * 64 + i * 16 + lr) * 32 + lq];
    }
#pragma unroll
    for (int i = 0; i < 4; ++i)
#pragma unroll
      for (int j = 0; j < 4; ++j) {
        acc[i][j] = __builtin_amdgcn_mfma_f32_16x16x32_f16(af[i], fh[j], acc[i][j], 0, 0, 0);
        acc[i][j] = __builtin_amdgcn_mfma_f32_16x16x32_f16(af[i], fl[j], acc[i][j], 0, 0, 0);
      }
    __syncthreads();
  }
#pragma unroll
  for (int i = 0; i < 4; ++i)
#pragma unroll
    for (int j = 0; j < 4; ++j) {
      int e = m0 + wm * 64 + i * 16 + (l >> 4) * 4;
      int d = n0 + wn * 64 + j * 16 + lr;
      f16x4 vh, vl;
#pragma unroll
      for (int r = 0; r < 4; ++r) {
        float v = acc[i][j][r] * invdeg[e + r];
        _Float16 hh = (_Float16)v;
        vh[r] = hh;
        vl[r] = (_Float16)(v - (float)hh);
      }
      size_t off = ((size_t)b * DD + d) * EE + e;
      *(f16x4*)&e1hi[off] = vh;
      *(f16x4*)&e1lo[off] = vl;
    }
}

// out1[b,e,d] = sum_f w2t[e,f]*edge1[d,f]; 3-term split MFMA -> fp32
__global__ __launch_bounds__(256) void k_out1(const _Float16* __restrict__ w2thi, const _Float16* __restrict__ w2tlo,
                                              const _Float16* __restrict__ e1hi, const _Float16* __restrict__ e1lo,
                                              float* __restrict__ out1) {
  __shared__ _Float16 smAh[128 * 32];
  __shared__ _Float16 smAl[128 * 32];
  __shared__ _Float16 smBh[128 * 32];
  __shared__ _Float16 smBl[128 * 32];
  int b = blockIdx.z;
  int m0 = blockIdx.x * 128;  // e
  int n0 = blockIdx.y * 128;  // d
  int t = threadIdx.x, w = t >> 6, l = t & 63;
  int wm = w >> 1, wn = w & 1;
  int lr = l & 15, lq = (l >> 4) * 8;
  int rA = l >> 2, cA = (l & 3) * 8;
  const _Float16* Bh = e1hi + (size_t)b * DD * EE;
  const _Float16* Bl = e1lo + (size_t)b * DD * EE;
  f32x4 acc[4][4];
  f32x4 z = {0.f, 0.f, 0.f, 0.f};
#pragma unroll
  for (int i = 0; i < 4; ++i)
#pragma unroll
    for (int j = 0; j < 4; ++j) acc[i][j] = z;
  for (int kk = 0; kk < EE; kk += 32) {
#pragma unroll
    for (int q = 0; q < 2; ++q) {
      int rr = (q * 4 + w) * 16 + rA;
      int lb = (q * 4 + w) * 512;
      gload16(w2thi + (size_t)(m0 + rr) * EE + kk + cA, smAh + lb);
      gload16(w2tlo + (size_t)(m0 + rr) * EE + kk + cA, smAl + lb);
      gload16(Bh + (size_t)(n0 + rr) * EE + kk + cA, smBh + lb);
      gload16(Bl + (size_t)(n0 + rr) * EE + kk + cA, smBl + lb);
    }
    __syncthreads();
    f16x8 ah[4], al[4], bh[4], bl[4];
#pragma unroll
    for (int i = 0; i < 4; ++i) {
      ah[i] = *(const f16x8*)&smAh[(wm * 64 + i * 16 + lr) * 32 + lq];
      al[i] = *(const f16x8*)&smAl[(wm * 64 + i * 16 + lr) * 32 + lq];
      bh[i] = *(const f16x8*)&smBh[(wn * 64 + i * 16 + lr) * 32 + lq];
      bl[i] = *(const f16x8*)&smBl[(wn * 64 + i * 16 + lr) * 32 + lq];
    }
#pragma unroll
    for (int i = 0; i < 4; ++i)
#pragma unroll
      for (int j = 0; j < 4; ++j) {
        acc[i][j] = __builtin_amdgcn_mfma_f32_16x16x32_f16(ah[i], bh[j], acc[i][j], 0, 0, 0);
        acc[i][j] = __builtin_amdgcn_mfma_f32_16x16x32_f16(ah[i], bl[j], acc[i][j], 0, 0, 0);
        acc[i][j] = __builtin_amdgcn_mfma_f32_16x16x32_f16(al[i], bh[j], acc[i][j], 0, 0, 0);
      }
    __syncthreads();
  }
#pragma unroll
  for (int i = 0; i < 4; ++i)
#pragma unroll
    for (int j = 0; j < 4; ++j) {
      int e = m0 + wm * 64 + i * 16 + (l >> 4) * 4;
      int d = n0 + wn * 64 + j * 16 + lr;
#pragma unroll
      for (int r = 0; r < 4; ++r) out1[((size_t)b * EE + e + r) * DD + d] = acc[i][j][r];
    }
}

// node_sc[b,n] = sum_d h[b,n,d]*a[d]
__global__ __launch_bounds__(256) void k_d1(const float* __restrict__ h, const float* __restrict__ a,
                                            float* __restrict__ node_sc) {
  int t = threadIdx.x;
  int w = t >> 6, l = t & 63;
  int row = blockIdx.x * 4 + w;
  float4 hv = *(const float4*)&h[(size_t)row * DD + l * 4];
  float4 av = *(const float4*)&a[l * 4];
  float s = hv.x * av.x + hv.y * av.y + hv.z * av.z + hv.w * av.w;
#pragma unroll
  for (int off = 32; off > 0; off >>= 1) s += __shfl_down(s, off);
  if (l == 0) node_sc[row] = s;
}

// edge_sc[b,e], time_e[b,e]
__global__ __launch_bounds__(256) void k_d2(const float* __restrict__ out1, const float* __restrict__ a,
                                            const float* __restrict__ a2, const float* __restrict__ pri_e,
                                            float* __restrict__ edge_sc, float* __restrict__ time_e) {
  int t = threadIdx.x;
  int w = t >> 6, l = t & 63;
  int row = blockIdx.x * 4 + w;
  float4 v = *(const float4*)&out1[(size_t)row * DD + l * 4];
  float4 av = *(const float4*)&a[DD + l * 4];
  float4 a2v = *(const float4*)&a2[l * 4];
  float s1 = v.x * av.x + v.y * av.y + v.z * av.z + v.w * av.w;
  float s2 = v.x * a2v.x + v.y * a2v.y + v.z * a2v.z + v.w * a2v.w;
#pragma unroll
  for (int off = 32; off > 0; off >>= 1) {
    s1 += __shfl_down(s1, off);
    s2 += __shfl_down(s2, off);
  }
  if (l == 0) {
    edge_sc[row] = s1;
    time_e[row] = lrelu(s2 + pri_e[row] * a2[DD]);
  }
}

// softmax stats over n per (b,e)
__global__ __launch_bounds__(256) void k_d3(const _Float16* __restrict__ incT, const float* __restrict__ node_sc,
                                            const float* __restrict__ edge_sc, const float* __restrict__ time_e,
                                            const float* __restrict__ a3, float* __restrict__ rmax,
                                            float* __restrict__ rinv) {
  int t = threadIdx.x;
  int w = t >> 6, l = t & 63;
  int row = blockIdx.x * 4 + w;
  int b = row >> 10;
  int e = row & (EE - 1);
  float a30 = a3[0], a31 = a3[1];
  float esc = edge_sc[row], te = time_e[row];
  float s2v[4];
  bool msk[4];
  float vmax = -3.0e38f;
#pragma unroll
  for (int q = 0; q < 4; ++q) {
    int n = l + q * 64;
    float ic = (float)incT[(size_t)e * NN + n];
    float s1 = lrelu(node_sc[(size_t)b * NN + n] + esc);
    float s2 = lrelu(te * a30 + s1 * a31);
    msk[q] = ic > 0.f;
    s2v[q] = s2;
    if (msk[q]) vmax = fmaxf(vmax, s2);
  }
#pragma unroll
  for (int off = 32; off > 0; off >>= 1) vmax = fmaxf(vmax, __shfl_xor(vmax, off));
  float ss = 0.f;
#pragma unroll
  for (int q = 0; q < 4; ++q)
    if (msk[q]) ss += __expf(s2v[q] - vmax);
#pragma unroll
  for (int off = 32; off > 0; off >>= 1) ss += __shfl_xor(ss, off);
  if (l == 0) {
    rmax[row] = vmax;
    rinv[row] = 1.0f / ss;
  }
}

// out0[b,d,n] = sum_e att[n,e]*out1[e,d]; att generated on the fly, fp16 MFMA
__global__ __launch_bounds__(256) void k_f(const float* __restrict__ out1, const _Float16* __restrict__ incT,
                                           const float* __restrict__ node_sc, const float* __restrict__ edge_sc,
                                           const float* __restrict__ time_e, const float* __restrict__ rmax,
                                           const float* __restrict__ rinv, const float* __restrict__ a3,
                                           float* __restrict__ out0) {
  __shared__ _Float16 smA[128 * 40];
  __shared__ _Float16 smB[128 * 40];
  __shared__ float smN[128];
  __shared__ float smE[32][4];
  int b = blockIdx.z;
  int m0 = blockIdx.x * 128;  // n
  int n0 = blockIdx.y * 128;  // d
  int t = threadIdx.x, w = t >> 6, l = t & 63;
  int wm = w >> 1, wn = w & 1;
  int lr = l & 15, lq = (l >> 4) * 8;
  float a30 = a3[0], a31 = a3[1];
  if (t < 128) smN[t] = node_sc[(size_t)b * NN + m0 + t];
  f32x4 acc[4][4];
  f32x4 z = {0.f, 0.f, 0.f, 0.f};
#pragma unroll
  for (int i = 0; i < 4; ++i)
#pragma unroll
    for (int j = 0; j < 4; ++j) acc[i][j] = z;
  int nl = t & 127, hf = t >> 7;
  for (int kk = 0; kk < EE; kk += 32) {
    __syncthreads();
    if (t < 32) {
      int row = b * EE + kk + t;
      smE[t][0] = edge_sc[row];
      smE[t][1] = time_e[row];
      smE[t][2] = rmax[row];
      smE[t][3] = rinv[row];
    }
    __syncthreads();
    float ns = smN[nl];
#pragma unroll
    for (int j = 0; j < 16; ++j) {
      int el = hf * 16 + j;
      float ic = (float)incT[(size_t)(kk + el) * NN + m0 + nl];
      float att = 0.0f;
      if (ic > 0.0f) {
        float s1 = lrelu(ns + smE[el][0]);
        float s2 = lrelu(smE[el][1] * a30 + s1 * a31);
        att = __expf(s2 - smE[el][2]) * smE[el][3];
      }
      smA[nl * 40 + el] = (_Float16)att;
      float bv = out1[((size_t)b * EE + kk + el) * DD + n0 + nl];
      smB[nl * 40 + el] = (_Float16)bv;
    }
    __syncthreads();
    f16x8 af[4], bf[4];
#pragma unroll
    for (int i = 0; i < 4; ++i) {
      af[i] = *(const f16x8*)&smA[(wm * 64 + i * 16 + lr) * 40 + lq];
      bf[i] = *(const f16x8*)&smB[(wn * 64 + i * 16 + lr) * 40 + lq];
    }
#pragma unroll
    for (int i = 0; i < 4; ++i)
#pragma unroll
      for (int j = 0; j < 4; ++j)
        acc[i][j] = __builtin_amdgcn_mfma_f32_16x16x32_f16(af[i], bf[j], acc[i][j], 0, 0, 0);
  }
#pragma unroll
  for (int i = 0; i < 4; ++i)
#pragma unroll
    for (int j = 0; j < 4; ++j) {
      int n = m0 + wm * 64 + i * 16 + (l >> 4) * 4;
      int d = n0 + wn * 64 + j * 16 + lr;
      *(float4*)&out0[((size_t)b * DD + d) * NN + n] =
          make_float4(acc[i][j][0], acc[i][j][1], acc[i][j][2], acc[i][j][3]);
    }
}

extern "C" void kernel_launch(void* const* d_in, const int* in_sizes, int n_in, void* d_out, int out_size,
                              void* d_ws, size_t ws_size, hipStream_t stream) {
  (void)in_sizes;
  (void)n_in;
  (void)out_size;
  (void)ws_size;
  const float* x = (const float*)d_in[0];
  const float* m = (const float*)d_in[1];
  const float* hid = (const float*)d_in[2];
  const float* pri_e = (const float*)d_in[3];
  const float* inc = (const float*)d_in[5];
  const float* W = (const float*)d_in[6];
  const float* bias = (const float*)d_in[7];
  const float* W2 = (const float*)d_in[8];
  const float* a = (const float*)d_in[9];
  const float* a2 = (const float*)d_in[10];
  const float* a3 = (const float*)d_in[11];

  float* out0 = (float*)d_out;                     // [B,D,N]; h fp32 scratch until k_f
  float* out1 = out0 + (size_t)BB * DD * NN;       // [B,E,D] fp32
  float* h = out0;
  _Float16* hThi = (_Float16*)out1;                // [B,D,N] fp16 (consumed before out1 written)
  _Float16* hTlo = hThi + (size_t)BB * DD * NN;

  _Float16* e1hi = (_Float16*)d_ws;                       // [B,D,E]
  _Float16* e1lo = e1hi + (size_t)BB * DD * EE;           // [B,D,E]
  _Float16* incT = e1lo + (size_t)BB * DD * EE;           // [E,N]
  _Float16* w2thi = incT + (size_t)EE * NN;               // [E,E]
  _Float16* w2tlo = w2thi + (size_t)EE * EE;              // [E,E]
  float* invdeg = (float*)(w2tlo + (size_t)EE * EE);      // E
  float* node_sc = invdeg + EE;                           // B*N
  float* edge_sc = node_sc + (size_t)BB * NN;             // B*E
  float* time_e = edge_sc + (size_t)BB * EE;              // B*E
  float* rmax = time_e + (size_t)BB * EE;                 // B*E
  float* rinv = rmax + (size_t)BB * EE;                   // B*E

  k_deg<<<dim3(EE / 256), 256, 0, stream>>>(inc, invdeg);
  k_incT<<<dim3(EE / 64, NN / 64), 256, 0, stream>>>(inc, incT);
  k_w2t<<<dim3(EE / 64, EE / 64), 256, 0, stream>>>(W2, w2thi, w2tlo);
  k_h<<<dim3(DD / 64, NN / 64, BB), 256, 0, stream>>>(x, m, hid, W, bias, h, hThi, hTlo);
  k_d1<<<dim3((BB * NN) / 4), 256, 0, stream>>>(h, a, node_sc);
  k_edge1<<<dim3(EE / 128, DD / 128, BB), 256, 0, stream>>>(incT, hThi, hTlo, invdeg, e1hi, e1lo);
  k_out1<<<dim3(EE / 128, DD / 128, BB), 256, 0, stream>>>(w2thi, w2tlo, e1hi, e1lo, out1);
  k_d2<<<dim3((BB * EE) / 4), 256, 0, stream>>>(out1, a, a2, pri_e, edge_sc, time_e);
  k_d3<<<dim3((BB * EE) / 4), 256, 0, stream>>>(incT, node_sc, edge_sc, time_e, a3, rmax, rinv);
  k_f<<<dim3(NN / 128, DD / 128, BB), 256, 0, stream>>>(out1, incT, node_sc, edge_sc, time_e, rmax, rinv, a3, out0);
}

// Round 3
// 256.716 us; speedup vs baseline: 2.5028x; 1.6584x over previous
//
#include <hip/hip_runtime.h>

#define BB 48
#define NN 256
#define EE 1024
#define DD 256
#define CIN 256

typedef __attribute__((ext_vector_type(4))) float f32x4;
typedef __attribute__((ext_vector_type(8))) _Float16 f16x8;
typedef __attribute__((ext_vector_type(4))) _Float16 f16x4;

__device__ __forceinline__ float lrelu(float t) { return t >= 0.0f ? t : 0.2f * t; }

__device__ __forceinline__ void gload16(const void* g, void* l) {
  __builtin_amdgcn_global_load_lds((const __attribute__((address_space(1))) void*)g,
                                   (__attribute__((address_space(3))) void*)l, 16, 0, 0);
}

// deg[e] = sum_n inc[n,e]; store 1/deg
__global__ __launch_bounds__(256) void k_deg(const float* __restrict__ inc, float* __restrict__ invdeg) {
  int e = blockIdx.x * 256 + threadIdx.x;
  float s = 0.f;
  for (int n = 0; n < NN; ++n) s += inc[(size_t)n * EE + e];
  invdeg[e] = 1.0f / s;
}

// incT[e,n] = inc[n,e]  (fp16, exact 0/1), LDS-tiled transpose
__global__ __launch_bounds__(256) void k_incT(const float* __restrict__ inc, _Float16* __restrict__ incT) {
  __shared__ float tile[64][65];
  int e0 = blockIdx.x * 64, n0 = blockIdx.y * 64;
  int t = threadIdx.x, c = t & 63, r = t >> 6;
#pragma unroll
  for (int i = 0; i < 16; ++i) tile[r + i * 4][c] = inc[(size_t)(n0 + r + i * 4) * EE + e0 + c];
  __syncthreads();
#pragma unroll
  for (int i = 0; i < 16; ++i) {
    int row = r + i * 4;
    incT[(size_t)(e0 + row) * NN + n0 + c] = (_Float16)tile[c][row];
  }
}

// W2T hi/lo fp16: w2t[e,f] = W2[f,e]
__global__ __launch_bounds__(256) void k_w2t(const float* __restrict__ W2, _Float16* __restrict__ hi,
                                             _Float16* __restrict__ lo) {
  __shared__ float tile[64][65];
  int f0 = blockIdx.x * 64, e0 = blockIdx.y * 64;
  int t = threadIdx.x, c = t & 63, r = t >> 6;
#pragma unroll
  for (int i = 0; i < 16; ++i) tile[r + i * 4][c] = W2[(size_t)(f0 + r + i * 4) * EE + e0 + c];
  __syncthreads();
#pragma unroll
  for (int i = 0; i < 16; ++i) {
    int row = r + i * 4;
    float v = tile[c][row];  // W2[f0+c][e0+row]
    _Float16 hh = (_Float16)v;
    hi[(size_t)(e0 + row) * EE + f0 + c] = hh;
    lo[(size_t)(e0 + row) * EE + f0 + c] = (_Float16)(v - (float)hh);
  }
}

// h[b,n,d] = sum_c x_in[b,c,n]*W[c,d] + bias[n]; also hT hi/lo fp16 [b,d,n]
__global__ __launch_bounds__(256) void k_h(const float* __restrict__ x, const float* __restrict__ m,
                                           const float* __restrict__ hid, const float* __restrict__ W,
                                           const float* __restrict__ bias, float* __restrict__ h,
                                           _Float16* __restrict__ hThi, _Float16* __restrict__ hTlo) {
  __shared__ float sa[16][68];
  __shared__ float sb[16][68];
  int b = blockIdx.z;
  int j0 = blockIdx.x * 64;  // d
  int i0 = blockIdx.y * 64;  // n
  int t = threadIdx.x;
  int tx = t & 15, ty = t >> 4;
  float acc[4][4] = {};
  for (int kk = 0; kk < CIN; kk += 16) {
    for (int r = 0; r < 4; ++r) {
      int idx = t + r * 256;
      int k = idx >> 6, i = idx & 63;
      int c = kk + k;
      const float* row;
      if (c < 96) row = x + ((size_t)b * 96 + c) * NN;
      else if (c < 192) row = m + ((size_t)b * 96 + (c - 96)) * NN;
      else row = hid + ((size_t)b * 64 + (c - 192)) * NN;
      sa[k][i] = row[i0 + i];
      sb[k][i] = W[(size_t)c * DD + j0 + i];
    }
    __syncthreads();
#pragma unroll
    for (int k = 0; k < 16; ++k) {
      float4 av = *(const float4*)&sa[k][ty * 4];
      float4 bv = *(const float4*)&sb[k][tx * 4];
      float ar[4] = {av.x, av.y, av.z, av.w};
      float br[4] = {bv.x, bv.y, bv.z, bv.w};
#pragma unroll
      for (int ii = 0; ii < 4; ++ii)
#pragma unroll
        for (int jj = 0; jj < 4; ++jj) acc[ii][jj] += ar[ii] * br[jj];
    }
    __syncthreads();
  }
  for (int ii = 0; ii < 4; ++ii) {
    int i = i0 + ty * 4 + ii;  // n
    float bv = bias[i];
    float4 v = make_float4(acc[ii][0] + bv, acc[ii][1] + bv, acc[ii][2] + bv, acc[ii][3] + bv);
    *(float4*)&h[((size_t)b * NN + i) * DD + j0 + tx * 4] = v;
  }
  _Float16* thb = hThi + (size_t)b * DD * NN;
  _Float16* tlb = hTlo + (size_t)b * DD * NN;
#pragma unroll
  for (int jj = 0; jj < 4; ++jj) {
    int d = j0 + tx * 4 + jj;
    f16x4 vh, vl;
#pragma unroll
    for (int ii = 0; ii < 4; ++ii) {
      float v = acc[ii][jj] + bias[i0 + ty * 4 + ii];
      _Float16 hh = (_Float16)v;
      vh[ii] = hh;
      vl[ii] = (_Float16)(v - (float)hh);
    }
    *(f16x4*)&thb[(size_t)d * NN + i0 + ty * 4] = vh;
    *(f16x4*)&tlb[(size_t)d * NN + i0 + ty * 4] = vl;
  }
}

// edge1[b,d,e] = (sum_n hT[d,n]*incT[e,n]) * invdeg[e]; 2-term MFMA, store hi/lo fp16
__global__ __launch_bounds__(256) void k_edge1(const _Float16* __restrict__ incT, const _Float16* __restrict__ hThi,
                                               const _Float16* __restrict__ hTlo, const float* __restrict__ invdeg,
                                               _Float16* __restrict__ e1hi, _Float16* __restrict__ e1lo) {
  __shared__ _Float16 smA[128 * 32];
  __shared__ _Float16 smBh[128 * 32];
  __shared__ _Float16 smBl[128 * 32];
  int b = blockIdx.z;
  int m0 = blockIdx.x * 128;  // e
  int n0 = blockIdx.y * 128;  // d
  int t = threadIdx.x, w = t >> 6, l = t & 63;
  int wm = w >> 1, wn = w & 1;
  int lr = l & 15, lq = (l >> 4) * 8;
  int rA = l >> 2, cA = (l & 3) * 8;
  const _Float16* Bh = hThi + (size_t)b * DD * NN;
  const _Float16* Bl = hTlo + (size_t)b * DD * NN;
  f32x4 acc[4][4];
  f32x4 z = {0.f, 0.f, 0.f, 0.f};
#pragma unroll
  for (int i = 0; i < 4; ++i)
#pragma unroll
    for (int j = 0; j < 4; ++j) acc[i][j] = z;
  for (int kk = 0; kk < NN; kk += 32) {
#pragma unroll
    for (int q = 0; q < 2; ++q) {
      int rr = (q * 4 + w) * 16 + rA;
      int lb = (q * 4 + w) * 512;
      gload16(incT + (size_t)(m0 + rr) * NN + kk + cA, smA + lb);
      gload16(Bh + (size_t)(n0 + rr) * NN + kk + cA, smBh + lb);
      gload16(Bl + (size_t)(n0 + rr) * NN + kk + cA, smBl + lb);
    }
    __syncthreads();
    f16x8 af[4], fh[4], fl[4];
#pragma unroll
    for (int i = 0; i < 4; ++i) {
      af[i] = *(const f16x8*)&smA[(wm * 64 + i * 16 + lr) * 32 + lq];
      fh[i] = *(const f16x8*)&smBh[(wn * 64 + i * 16 + lr) * 32 + lq];
      fl[i] = *(const f16x8*)&smBl[(wn * 64 + i * 16 + lr) * 32 + lq];
    }
#pragma unroll
    for (int i = 0; i < 4; ++i)
#pragma unroll
      for (int j = 0; j < 4; ++j) {
        acc[i][j] = __builtin_amdgcn_mfma_f32_16x16x32_f16(af[i], fh[j], acc[i][j], 0, 0, 0);
        acc[i][j] = __builtin_amdgcn_mfma_f32_16x16x32_f16(af[i], fl[j], acc[i][j], 0, 0, 0);
      }
    __syncthreads();
  }
#pragma unroll
  for (int i = 0; i < 4; ++i)
#pragma unroll
    for (int j = 0; j < 4; ++j) {
      int e = m0 + wm * 64 + i * 16 + (l >> 4) * 4;
      int d = n0 + wn * 64 + j * 16 + lr;
      f16x4 vh, vl;
#pragma unroll
      for (int r = 0; r < 4; ++r) {
        float v = acc[i][j][r] * invdeg[e + r];
        _Float16 hh = (_Float16)v;
        vh[r] = hh;
        vl[r] = (_Float16)(v - (float)hh);
      }
      size_t off = ((size_t)b * DD + d) * EE + e;
      *(f16x4*)&e1hi[off] = vh;
      *(f16x4*)&e1lo[off] = vl;
    }
}

// out1[b,e,d] = sum_f w2t[e,f]*edge1[d,f]; 3-term split MFMA -> fp32
__global__ __launch_bounds__(256) void k_out1(const _Float16* __restrict__ w2thi, const _Float16* __restrict__ w2tlo,
                                              const _Float16* __restrict__ e1hi, const _Float16* __restrict__ e1lo,
                                              float* __restrict__ out1) {
  __shared__ _Float16 smAh[128 * 32];
  __shared__ _Float16 smAl[128 * 32];
  __shared__ _Float16 smBh[128 * 32];
  __shared__ _Float16 smBl[128 * 32];
  int b = blockIdx.z;
  int m0 = blockIdx.x * 128;  // e
  int n0 = blockIdx.y * 128;  // d
  int t = threadIdx.x, w = t >> 6, l = t & 63;
  int wm = w >> 1, wn = w & 1;
  int lr = l & 15, lq = (l >> 4) * 8;
  int rA = l >> 2, cA = (l & 3) * 8;
  const _Float16* Bh = e1hi + (size_t)b * DD * EE;
  const _Float16* Bl = e1lo + (size_t)b * DD * EE;
  f32x4 acc[4][4];
  f32x4 z = {0.f, 0.f, 0.f, 0.f};
#pragma unroll
  for (int i = 0; i < 4; ++i)
#pragma unroll
    for (int j = 0; j < 4; ++j) acc[i][j] = z;
  for (int kk = 0; kk < EE; kk += 32) {
#pragma unroll
    for (int q = 0; q < 2; ++q) {
      int rr = (q * 4 + w) * 16 + rA;
      int lb = (q * 4 + w) * 512;
      gload16(w2thi + (size_t)(m0 + rr) * EE + kk + cA, smAh + lb);
      gload16(w2tlo + (size_t)(m0 + rr) * EE + kk + cA, smAl + lb);
      gload16(Bh + (size_t)(n0 + rr) * EE + kk + cA, smBh + lb);
      gload16(Bl + (size_t)(n0 + rr) * EE + kk + cA, smBl + lb);
    }
    __syncthreads();
    f16x8 ah[4], al[4], bh[4], bl[4];
#pragma unroll
    for (int i = 0; i < 4; ++i) {
      ah[i] = *(const f16x8*)&smAh[(wm * 64 + i * 16 + lr) * 32 + lq];
      al[i] = *(const f16x8*)&smAl[(wm * 64 + i * 16 + lr) * 32 + lq];
      bh[i] = *(const f16x8*)&smBh[(wn * 64 + i * 16 + lr) * 32 + lq];
      bl[i] = *(const f16x8*)&smBl[(wn * 64 + i * 16 + lr) * 32 + lq];
    }
#pragma unroll
    for (int i = 0; i < 4; ++i)
#pragma unroll
      for (int j = 0; j < 4; ++j) {
        acc[i][j] = __builtin_amdgcn_mfma_f32_16x16x32_f16(ah[i], bh[j], acc[i][j], 0, 0, 0);
        acc[i][j] = __builtin_amdgcn_mfma_f32_16x16x32_f16(ah[i], bl[j], acc[i][j], 0, 0, 0);
        acc[i][j] = __builtin_amdgcn_mfma_f32_16x16x32_f16(al[i], bh[j], acc[i][j], 0, 0, 0);
      }
    __syncthreads();
  }
#pragma unroll
  for (int i = 0; i < 4; ++i)
#pragma unroll
    for (int j = 0; j < 4; ++j) {
      int e = m0 + wm * 64 + i * 16 + (l >> 4) * 4;
      int d = n0 + wn * 64 + j * 16 + lr;
#pragma unroll
      for (int r = 0; r < 4; ++r) out1[((size_t)b * EE + e + r) * DD + d] = acc[i][j][r];
    }
}

// node_sc[b,n] = sum_d h[b,n,d]*a[d]
__global__ __launch_bounds__(256) void k_d1(const float* __restrict__ h, const float* __restrict__ a,
                                            float* __restrict__ node_sc) {
  int t = threadIdx.x;
  int w = t >> 6, l = t & 63;
  int row = blockIdx.x * 4 + w;
  float4 hv = *(const float4*)&h[(size_t)row * DD + l * 4];
  float4 av = *(const float4*)&a[l * 4];
  float s = hv.x * av.x + hv.y * av.y + hv.z * av.z + hv.w * av.w;
#pragma unroll
  for (int off = 32; off > 0; off >>= 1) s += __shfl_down(s, off);
  if (l == 0) node_sc[row] = s;
}

// edge_sc[b,e], time_e[b,e]
__global__ __launch_bounds__(256) void k_d2(const float* __restrict__ out1, const float* __restrict__ a,
                                            const float* __restrict__ a2, const float* __restrict__ pri_e,
                                            float* __restrict__ edge_sc, float* __restrict__ time_e) {
  int t = threadIdx.x;
  int w = t >> 6, l = t & 63;
  int row = blockIdx.x * 4 + w;
  float4 v = *(const float4*)&out1[(size_t)row * DD + l * 4];
  float4 av = *(const float4*)&a[DD + l * 4];
  float4 a2v = *(const float4*)&a2[l * 4];
  float s1 = v.x * av.x + v.y * av.y + v.z * av.z + v.w * av.w;
  float s2 = v.x * a2v.x + v.y * a2v.y + v.z * a2v.z + v.w * a2v.w;
#pragma unroll
  for (int off = 32; off > 0; off >>= 1) {
    s1 += __shfl_down(s1, off);
    s2 += __shfl_down(s2, off);
  }
  if (l == 0) {
    edge_sc[row] = s1;
    time_e[row] = lrelu(s2 + pri_e[row] * a2[DD]);
  }
}

// softmax stats over n per (b,e)
__global__ __launch_bounds__(256) void k_d3(const _Float16* __restrict__ incT, const float* __restrict__ node_sc,
                                            const float* __restrict__ edge_sc, const float* __restrict__ time_e,
                                            const float* __restrict__ a3, float* __restrict__ rmax,
                                            float* __restrict__ rinv) {
  int t = threadIdx.x;
  int w = t >> 6, l = t & 63;
  int row = blockIdx.x * 4 + w;
  int b = row >> 10;
  int e = row & (EE - 1);
  float a30 = a3[0], a31 = a3[1];
  float esc = edge_sc[row], te = time_e[row];
  float s2v[4];
  bool msk[4];
  float vmax = -3.0e38f;
#pragma unroll
  for (int q = 0; q < 4; ++q) {
    int n = l + q * 64;
    float ic = (float)incT[(size_t)e * NN + n];
    float s1 = lrelu(node_sc[(size_t)b * NN + n] + esc);
    float s2 = lrelu(te * a30 + s1 * a31);
    msk[q] = ic > 0.f;
    s2v[q] = s2;
    if (msk[q]) vmax = fmaxf(vmax, s2);
  }
#pragma unroll
  for (int off = 32; off > 0; off >>= 1) vmax = fmaxf(vmax, __shfl_xor(vmax, off));
  float ss = 0.f;
#pragma unroll
  for (int q = 0; q < 4; ++q)
    if (msk[q]) ss += __expf(s2v[q] - vmax);
#pragma unroll
  for (int off = 32; off > 0; off >>= 1) ss += __shfl_xor(ss, off);
  if (l == 0) {
    rmax[row] = vmax;
    rinv[row] = 1.0f / ss;
  }
}

// out1T16[b,d,e] = fp16(out1[b,e,d])
__global__ __launch_bounds__(256) void k_t16(const float* __restrict__ out1, _Float16* __restrict__ out1T) {
  __shared__ float tile[64][65];
  int b = blockIdx.z;
  int e0 = blockIdx.x * 64, d0 = blockIdx.y * 64;
  const float* src = out1 + (size_t)b * EE * DD;
  _Float16* dst = out1T + (size_t)b * DD * EE;
  int t = threadIdx.x, c = t & 63, r = t >> 6;
#pragma unroll
  for (int i = 0; i < 16; ++i) tile[r + i * 4][c] = src[(size_t)(e0 + r + i * 4) * DD + d0 + c];
  __syncthreads();
#pragma unroll
  for (int i = 0; i < 16; ++i) {
    int row = r + i * 4;
    dst[(size_t)(d0 + row) * EE + e0 + c] = (_Float16)tile[c][row];
  }
}

// att16[b,n,e] = softmax coefficient (fp16), computed from stats
__global__ __launch_bounds__(256) void k_att(const float* __restrict__ inc, const float* __restrict__ node_sc,
                                             const float* __restrict__ edge_sc, const float* __restrict__ time_e,
                                             const float* __restrict__ rmax, const float* __restrict__ rinv,
                                             const float* __restrict__ a3, _Float16* __restrict__ att16) {
  int n = blockIdx.x, b = blockIdx.y;
  int e = threadIdx.x * 4;
  float a30 = a3[0], a31 = a3[1];
  float ns = node_sc[b * NN + n];
  float4 icv = *(const float4*)&inc[(size_t)n * EE + e];
  int be = b * EE + e;
  float4 esc = *(const float4*)&edge_sc[be];
  float4 te = *(const float4*)&time_e[be];
  float4 rm = *(const float4*)&rmax[be];
  float4 ri = *(const float4*)&rinv[be];
  float ica[4] = {icv.x, icv.y, icv.z, icv.w};
  float ea[4] = {esc.x, esc.y, esc.z, esc.w};
  float ta[4] = {te.x, te.y, te.z, te.w};
  float ma[4] = {rm.x, rm.y, rm.z, rm.w};
  float ra[4] = {ri.x, ri.y, ri.z, ri.w};
  f16x4 o;
#pragma unroll
  for (int q = 0; q < 4; ++q) {
    float att = 0.f;
    if (ica[q] > 0.f) {
      float s1 = lrelu(ns + ea[q]);
      float s2 = lrelu(ta[q] * a30 + s1 * a31);
      att = __expf(s2 - ma[q]) * ra[q];
    }
    o[q] = (_Float16)att;
  }
  *(f16x4*)&att16[((size_t)b * NN + n) * EE + e] = o;
}

// out0[b,d,n] = sum_e att16[n,e]*out1T16[d,e]; fp16 MFMA, swizzled LDS
__global__ __launch_bounds__(256) void k_fgemm(const _Float16* __restrict__ att16, const _Float16* __restrict__ out1T,
                                               float* __restrict__ out0) {
  __shared__ _Float16 smA[64 * 64];
  __shared__ _Float16 smB[64 * 64];
  int b = blockIdx.z;
  int n0 = blockIdx.x * 64, d0 = blockIdx.y * 64;
  int t = threadIdx.x, w = t >> 6, l = t & 63;
  int wm = w >> 1, wn = w & 1;
  int lr = l & 15;
  const _Float16* A = att16 + ((size_t)b * NN + n0) * EE;
  const _Float16* Bp = out1T + ((size_t)b * DD + d0) * EE;
  int lrow = l >> 3;                       // 0..7 within the 8-row chunk
  int scol = 8 * ((l & 7) ^ (lrow & 7));   // pre-swizzled source column (f16 elems)
  f32x4 acc[2][2];
  f32x4 z = {0.f, 0.f, 0.f, 0.f};
#pragma unroll
  for (int i = 0; i < 2; ++i)
#pragma unroll
    for (int j = 0; j < 2; ++j) acc[i][j] = z;
  for (int kk = 0; kk < EE; kk += 64) {
#pragma unroll
    for (int q = 0; q < 2; ++q) {
      int row = q * 32 + w * 8 + lrow;
      int lb = (q * 32 + w * 8) * 64;  // f16 elems; lane adds 16B*l
      gload16(A + (size_t)row * EE + kk + scol, smA + lb);
      gload16(Bp + (size_t)row * EE + kk + scol, smB + lb);
    }
    __syncthreads();
    f16x8 af[2][2], bf[2][2];
#pragma unroll
    for (int i = 0; i < 2; ++i)
#pragma unroll
      for (int ks = 0; ks < 2; ++ks) {
        int ra = wm * 32 + i * 16 + lr;
        af[i][ks] = *(const f16x8*)&smA[ra * 64 + ((ks * 32 + (l >> 4) * 8) ^ ((ra & 7) << 3))];
        int rb = wn * 32 + i * 16 + lr;
        bf[i][ks] = *(const f16x8*)&smB[rb * 64 + ((ks * 32 + (l >> 4) * 8) ^ ((rb & 7) << 3))];
      }
#pragma unroll
    for (int ks = 0; ks < 2; ++ks)
#pragma unroll
      for (int i = 0; i < 2; ++i)
#pragma unroll
        for (int j = 0; j < 2; ++j)
          acc[i][j] = __builtin_amdgcn_mfma_f32_16x16x32_f16(af[i][ks], bf[j][ks], acc[i][j], 0, 0, 0);
    __syncthreads();
  }
  float* ob = out0 + (size_t)b * DD * NN;
#pragma unroll
  for (int i = 0; i < 2; ++i)
#pragma unroll
    for (int j = 0; j < 2; ++j) {
      int n = n0 + wm * 32 + i * 16 + (l >> 4) * 4;
      int d = d0 + wn * 32 + j * 16 + lr;
      *(float4*)&ob[(size_t)d * NN + n] =
          make_float4(acc[i][j][0], acc[i][j][1], acc[i][j][2], acc[i][j][3]);
    }
}

extern "C" void kernel_launch(void* const* d_in, const int* in_sizes, int n_in, void* d_out, int out_size,
                              void* d_ws, size_t ws_size, hipStream_t stream) {
  (void)in_sizes;
  (void)n_in;
  (void)out_size;
  (void)ws_size;
  const float* x = (const float*)d_in[0];
  const float* m = (const float*)d_in[1];
  const float* hid = (const float*)d_in[2];
  const float* pri_e = (const float*)d_in[3];
  const float* inc = (const float*)d_in[5];
  const float* W = (const float*)d_in[6];
  const float* bias = (const float*)d_in[7];
  const float* W2 = (const float*)d_in[8];
  const float* a = (const float*)d_in[9];
  const float* a2 = (const float*)d_in[10];
  const float* a3 = (const float*)d_in[11];

  float* out0 = (float*)d_out;                // [B,D,N]; h fp32 scratch until k_fgemm
  float* out1 = out0 + (size_t)BB * DD * NN;  // [B,E,D] fp32
  float* h = out0;
  _Float16* hThi = (_Float16*)out1;  // [B,D,N] fp16 (consumed before out1 written)
  _Float16* hTlo = hThi + (size_t)BB * DD * NN;

  _Float16* e1hi = (_Float16*)d_ws;              // [B,D,E]
  _Float16* e1lo = e1hi + (size_t)BB * DD * EE;  // [B,D,E]
  _Float16* out1T16 = e1hi;                      // alias: live only after k_out1
  _Float16* att16 = e1lo;                        // alias: live only after k_out1
  _Float16* incT = e1lo + (size_t)BB * DD * EE;  // [E,N]
  _Float16* w2thi = incT + (size_t)EE * NN;      // [E,E]
  _Float16* w2tlo = w2thi + (size_t)EE * EE;     // [E,E]
  float* invdeg = (float*)(w2tlo + (size_t)EE * EE);  // E
  float* node_sc = invdeg + EE;                       // B*N
  float* edge_sc = node_sc + (size_t)BB * NN;         // B*E
  float* time_e = edge_sc + (size_t)BB * EE;          // B*E
  float* rmax = time_e + (size_t)BB * EE;             // B*E
  float* rinv = rmax + (size_t)BB * EE;               // B*E

  k_deg<<<dim3(EE / 256), 256, 0, stream>>>(inc, invdeg);
  k_incT<<<dim3(EE / 64, NN / 64), 256, 0, stream>>>(inc, incT);
  k_w2t<<<dim3(EE / 64, EE / 64), 256, 0, stream>>>(W2, w2thi, w2tlo);
  k_h<<<dim3(DD / 64, NN / 64, BB), 256, 0, stream>>>(x, m, hid, W, bias, h, hThi, hTlo);
  k_d1<<<dim3((BB * NN) / 4), 256, 0, stream>>>(h, a, node_sc);
  k_edge1<<<dim3(EE / 128, DD / 128, BB), 256, 0, stream>>>(incT, hThi, hTlo, invdeg, e1hi, e1lo);
  k_out1<<<dim3(EE / 128, DD / 128, BB), 256, 0, stream>>>(w2thi, w2tlo, e1hi, e1lo, out1);
  k_d2<<<dim3((BB * EE) / 4), 256, 0, stream>>>(out1, a, a2, pri_e, edge_sc, time_e);
  k_d3<<<dim3((BB * EE) / 4), 256, 0, stream>>>(incT, node_sc, edge_sc, time_e, a3, rmax, rinv);
  k_t16<<<dim3(EE / 64, DD / 64, BB), 256, 0, stream>>>(out1, out1T16);
  k_att<<<dim3(NN, BB), 256, 0, stream>>>(inc, node_sc, edge_sc, time_e, rmax, rinv, a3, att16);
  k_fgemm<<<dim3(NN / 64, DD / 64, BB), 256, 0, stream>>>(att16, out1T16, out0);
}

// Round 4
// 230.390 us; speedup vs baseline: 2.7888x; 1.1143x over previous
//
#include <hip/hip_runtime.h>

#define BB 48
#define NN 256
#define EE 1024
#define DD 256
#define CIN 256

typedef __attribute__((ext_vector_type(4))) float f32x4;
typedef __attribute__((ext_vector_type(8))) _Float16 f16x8;
typedef __attribute__((ext_vector_type(4))) _Float16 f16x4;

__device__ __forceinline__ float lrelu(float t) { return t >= 0.0f ? t : 0.2f * t; }

__device__ __forceinline__ void gload16(const void* g, void* l) {
  __builtin_amdgcn_global_load_lds((const __attribute__((address_space(1))) void*)g,
                                   (__attribute__((address_space(3))) void*)l, 16, 0, 0);
}

// deg[e] = sum_n inc[n,e]; store 1/deg
__global__ __launch_bounds__(256) void k_deg(const float* __restrict__ inc, float* __restrict__ invdeg) {
  int e = blockIdx.x * 256 + threadIdx.x;
  float s = 0.f;
  for (int n = 0; n < NN; ++n) s += inc[(size_t)n * EE + e];
  invdeg[e] = 1.0f / s;
}

// incT[e,n] = inc[n,e]  (fp16, exact 0/1), LDS-tiled transpose
__global__ __launch_bounds__(256) void k_incT(const float* __restrict__ inc, _Float16* __restrict__ incT) {
  __shared__ float tile[64][65];
  int e0 = blockIdx.x * 64, n0 = blockIdx.y * 64;
  int t = threadIdx.x, c = t & 63, r = t >> 6;
#pragma unroll
  for (int i = 0; i < 16; ++i) tile[r + i * 4][c] = inc[(size_t)(n0 + r + i * 4) * EE + e0 + c];
  __syncthreads();
#pragma unroll
  for (int i = 0; i < 16; ++i) {
    int row = r + i * 4;
    incT[(size_t)(e0 + row) * NN + n0 + c] = (_Float16)tile[c][row];
  }
}

// w2t[e,f] = fp16(W2[f,e])  (hi only; scores use fp32 W2 directly)
__global__ __launch_bounds__(256) void k_w2t(const float* __restrict__ W2, _Float16* __restrict__ hi) {
  __shared__ float tile[64][65];
  int f0 = blockIdx.x * 64, e0 = blockIdx.y * 64;
  int t = threadIdx.x, c = t & 63, r = t >> 6;
#pragma unroll
  for (int i = 0; i < 16; ++i) tile[r + i * 4][c] = W2[(size_t)(f0 + r + i * 4) * EE + e0 + c];
  __syncthreads();
#pragma unroll
  for (int i = 0; i < 16; ++i) {
    int row = r + i * 4;
    hi[(size_t)(e0 + row) * EE + f0 + c] = (_Float16)tile[c][row];
  }
}

// h[b,n,d] = sum_c x_in[b,c,n]*W[c,d] + bias[n]; also hT hi/lo fp16 [b,d,n]
__global__ __launch_bounds__(256) void k_h(const float* __restrict__ x, const float* __restrict__ m,
                                           const float* __restrict__ hid, const float* __restrict__ W,
                                           const float* __restrict__ bias, float* __restrict__ h,
                                           _Float16* __restrict__ hThi, _Float16* __restrict__ hTlo) {
  __shared__ float sa[16][68];
  __shared__ float sb[16][68];
  int b = blockIdx.z;
  int j0 = blockIdx.x * 64;  // d
  int i0 = blockIdx.y * 64;  // n
  int t = threadIdx.x;
  int tx = t & 15, ty = t >> 4;
  float acc[4][4] = {};
  for (int kk = 0; kk < CIN; kk += 16) {
    for (int r = 0; r < 4; ++r) {
      int idx = t + r * 256;
      int k = idx >> 6, i = idx & 63;
      int c = kk + k;
      const float* row;
      if (c < 96) row = x + ((size_t)b * 96 + c) * NN;
      else if (c < 192) row = m + ((size_t)b * 96 + (c - 96)) * NN;
      else row = hid + ((size_t)b * 64 + (c - 192)) * NN;
      sa[k][i] = row[i0 + i];
      sb[k][i] = W[(size_t)c * DD + j0 + i];
    }
    __syncthreads();
#pragma unroll
    for (int k = 0; k < 16; ++k) {
      float4 av = *(const float4*)&sa[k][ty * 4];
      float4 bv = *(const float4*)&sb[k][tx * 4];
      float ar[4] = {av.x, av.y, av.z, av.w};
      float br[4] = {bv.x, bv.y, bv.z, bv.w};
#pragma unroll
      for (int ii = 0; ii < 4; ++ii)
#pragma unroll
        for (int jj = 0; jj < 4; ++jj) acc[ii][jj] += ar[ii] * br[jj];
    }
    __syncthreads();
  }
  for (int ii = 0; ii < 4; ++ii) {
    int i = i0 + ty * 4 + ii;  // n
    float bv = bias[i];
    float4 v = make_float4(acc[ii][0] + bv, acc[ii][1] + bv, acc[ii][2] + bv, acc[ii][3] + bv);
    *(float4*)&h[((size_t)b * NN + i) * DD + j0 + tx * 4] = v;
  }
  _Float16* thb = hThi + (size_t)b * DD * NN;
  _Float16* tlb = hTlo + (size_t)b * DD * NN;
#pragma unroll
  for (int jj = 0; jj < 4; ++jj) {
    int d = j0 + tx * 4 + jj;
    f16x4 vh, vl;
#pragma unroll
    for (int ii = 0; ii < 4; ++ii) {
      float v = acc[ii][jj] + bias[i0 + ty * 4 + ii];
      _Float16 hh = (_Float16)v;
      vh[ii] = hh;
      vl[ii] = (_Float16)(v - (float)hh);
    }
    *(f16x4*)&thb[(size_t)d * NN + i0 + ty * 4] = vh;
    *(f16x4*)&tlb[(size_t)d * NN + i0 + ty * 4] = vl;
  }
}

// edge1[b,d,e] = (sum_n hT[d,n]*incT[e,n]) * invdeg[e]; 2-term MFMA, store hi/lo fp16
__global__ __launch_bounds__(256) void k_edge1(const _Float16* __restrict__ incT, const _Float16* __restrict__ hThi,
                                               const _Float16* __restrict__ hTlo, const float* __restrict__ invdeg,
                                               _Float16* __restrict__ e1hi, _Float16* __restrict__ e1lo) {
  __shared__ _Float16 smA[128 * 32];
  __shared__ _Float16 smBh[128 * 32];
  __shared__ _Float16 smBl[128 * 32];
  int b = blockIdx.z;
  int m0 = blockIdx.x * 128;  // e
  int n0 = blockIdx.y * 128;  // d
  int t = threadIdx.x, w = t >> 6, l = t & 63;
  int wm = w >> 1, wn = w & 1;
  int lr = l & 15, lq = (l >> 4) * 8;
  int rA = l >> 2, cA = (l & 3) * 8;
  const _Float16* Bh = hThi + (size_t)b * DD * NN;
  const _Float16* Bl = hTlo + (size_t)b * DD * NN;
  f32x4 acc[4][4];
  f32x4 z = {0.f, 0.f, 0.f, 0.f};
#pragma unroll
  for (int i = 0; i < 4; ++i)
#pragma unroll
    for (int j = 0; j < 4; ++j) acc[i][j] = z;
  for (int kk = 0; kk < NN; kk += 32) {
#pragma unroll
    for (int q = 0; q < 2; ++q) {
      int rr = (q * 4 + w) * 16 + rA;
      int lb = (q * 4 + w) * 512;
      gload16(incT + (size_t)(m0 + rr) * NN + kk + cA, smA + lb);
      gload16(Bh + (size_t)(n0 + rr) * NN + kk + cA, smBh + lb);
      gload16(Bl + (size_t)(n0 + rr) * NN + kk + cA, smBl + lb);
    }
    __syncthreads();
    f16x8 af[4], fh[4], fl[4];
#pragma unroll
    for (int i = 0; i < 4; ++i) {
      af[i] = *(const f16x8*)&smA[(wm * 64 + i * 16 + lr) * 32 + lq];
      fh[i] = *(const f16x8*)&smBh[(wn * 64 + i * 16 + lr) * 32 + lq];
      fl[i] = *(const f16x8*)&smBl[(wn * 64 + i * 16 + lr) * 32 + lq];
    }
#pragma unroll
    for (int i = 0; i < 4; ++i)
#pragma unroll
      for (int j = 0; j < 4; ++j) {
        acc[i][j] = __builtin_amdgcn_mfma_f32_16x16x32_f16(af[i], fh[j], acc[i][j], 0, 0, 0);
        acc[i][j] = __builtin_amdgcn_mfma_f32_16x16x32_f16(af[i], fl[j], acc[i][j], 0, 0, 0);
      }
    __syncthreads();
  }
#pragma unroll
  for (int i = 0; i < 4; ++i)
#pragma unroll
    for (int j = 0; j < 4; ++j) {
      int e = m0 + wm * 64 + i * 16 + (l >> 4) * 4;
      int d = n0 + wn * 64 + j * 16 + lr;
      f16x4 vh, vl;
#pragma unroll
      for (int r = 0; r < 4; ++r) {
        float v = acc[i][j][r] * invdeg[e + r];
        _Float16 hh = (_Float16)v;
        vh[r] = hh;
        vl[r] = (_Float16)(v - (float)hh);
      }
      size_t off = ((size_t)b * DD + d) * EE + e;
      *(f16x4*)&e1hi[off] = vh;
      *(f16x4*)&e1lo[off] = vl;
    }
}

// u1[b,f] = sum_d e1[b,d,f]*a[D+d];  u2[b,f] = sum_d e1[b,d,f]*a2[d]   (fp32-accurate from hi+lo)
__global__ __launch_bounds__(256) void k_u(const _Float16* __restrict__ e1hi, const _Float16* __restrict__ e1lo,
                                           const float* __restrict__ a, const float* __restrict__ a2,
                                           float* __restrict__ u1, float* __restrict__ u2) {
  __shared__ float sa[DD], sa2[DD];
  __shared__ float r1[4][64], r2[4][64];
  int b = blockIdx.y;
  int f0 = blockIdx.x * 64;
  int t = threadIdx.x;
  if (t < DD) {
    sa[t] = a[DD + t];
    sa2[t] = a2[t];
  }
  __syncthreads();
  int fl = t & 63, dg = t >> 6;
  int f = f0 + fl;
  float s1 = 0.f, s2 = 0.f;
  const _Float16* ph = e1hi + ((size_t)b * DD + dg * 64) * EE + f;
  const _Float16* pl = e1lo + ((size_t)b * DD + dg * 64) * EE + f;
  for (int i = 0; i < 64; ++i) {
    float v = (float)ph[(size_t)i * EE] + (float)pl[(size_t)i * EE];
    int d = dg * 64 + i;
    s1 += v * sa[d];
    s2 += v * sa2[d];
  }
  r1[dg][fl] = s1;
  r2[dg][fl] = s2;
  __syncthreads();
  if (t < 64) {
    u1[(size_t)b * EE + f0 + t] = r1[0][t] + r1[1][t] + r1[2][t] + r1[3][t];
    u2[(size_t)b * EE + f0 + t] = r2[0][t] + r2[1][t] + r2[2][t] + r2[3][t];
  }
}

// edge_sc[b,e] = sum_f W2[f,e]*u1[b,f];  time_e[b,e] = lrelu(sum_f W2[f,e]*u2[b,f] + pri_e*a2[D])
__global__ __launch_bounds__(256) void k_esc(const float* __restrict__ W2, const float* __restrict__ u1,
                                             const float* __restrict__ u2, const float* __restrict__ pri_e,
                                             const float* __restrict__ a2, float* __restrict__ edge_sc,
                                             float* __restrict__ time_e) {
  __shared__ float su1[EE], su2[EE];
  __shared__ float r1[4][64], r2[4][64];
  int b = blockIdx.y;
  int e0 = blockIdx.x * 64;
  int t = threadIdx.x;
  *(float4*)&su1[t * 4] = *(const float4*)&u1[(size_t)b * EE + t * 4];
  *(float4*)&su2[t * 4] = *(const float4*)&u2[(size_t)b * EE + t * 4];
  __syncthreads();
  int el = t & 63, fg = t >> 6;
  int e = e0 + el;
  float s1 = 0.f, s2 = 0.f;
  for (int i = 0; i < 256; ++i) {
    int f = fg * 256 + i;
    float w = W2[(size_t)f * EE + e];
    s1 += w * su1[f];
    s2 += w * su2[f];
  }
  r1[fg][el] = s1;
  r2[fg][el] = s2;
  __syncthreads();
  if (t < 64) {
    int row = b * EE + e0 + t;
    edge_sc[row] = r1[0][t] + r1[1][t] + r1[2][t] + r1[3][t];
    time_e[row] = lrelu(r2[0][t] + r2[1][t] + r2[2][t] + r2[3][t] + pri_e[row] * a2[DD]);
  }
}

// softmax stats over n per (b,e)
__global__ __launch_bounds__(256) void k_d3(const _Float16* __restrict__ incT, const float* __restrict__ node_sc,
                                            const float* __restrict__ edge_sc, const float* __restrict__ time_e,
                                            const float* __restrict__ a3, float* __restrict__ rmax,
                                            float* __restrict__ rinv) {
  int t = threadIdx.x;
  int w = t >> 6, l = t & 63;
  int row = blockIdx.x * 4 + w;
  int b = row >> 10;
  int e = row & (EE - 1);
  float a30 = a3[0], a31 = a3[1];
  float esc = edge_sc[row], te = time_e[row];
  float s2v[4];
  bool msk[4];
  float vmax = -3.0e38f;
#pragma unroll
  for (int q = 0; q < 4; ++q) {
    int n = l + q * 64;
    float ic = (float)incT[(size_t)e * NN + n];
    float s1 = lrelu(node_sc[(size_t)b * NN + n] + esc);
    float s2 = lrelu(te * a30 + s1 * a31);
    msk[q] = ic > 0.f;
    s2v[q] = s2;
    if (msk[q]) vmax = fmaxf(vmax, s2);
  }
#pragma unroll
  for (int off = 32; off > 0; off >>= 1) vmax = fmaxf(vmax, __shfl_xor(vmax, off));
  float ss = 0.f;
#pragma unroll
  for (int q = 0; q < 4; ++q)
    if (msk[q]) ss += __expf(s2v[q] - vmax);
#pragma unroll
  for (int off = 32; off > 0; off >>= 1) ss += __shfl_xor(ss, off);
  if (l == 0) {
    rmax[row] = vmax;
    rinv[row] = 1.0f / ss;
  }
}

// out1[b,e,d] = sum_f w2t[e,f]*e1hi[d,f]; plain fp16 MFMA; also emits out1T16[b,d,e]
__global__ __launch_bounds__(256) void k_out1(const _Float16* __restrict__ w2thi, const _Float16* __restrict__ e1hi,
                                              float* __restrict__ out1, _Float16* __restrict__ out1T) {
  __shared__ _Float16 smA[128 * 32];
  __shared__ _Float16 smB[128 * 32];
  int b = blockIdx.z;
  int m0 = blockIdx.x * 128;  // e
  int n0 = blockIdx.y * 128;  // d
  int t = threadIdx.x, w = t >> 6, l = t & 63;
  int wm = w >> 1, wn = w & 1;
  int lr = l & 15, lq = (l >> 4) * 8;
  int rA = l >> 2, cA = (l & 3) * 8;
  const _Float16* Bh = e1hi + (size_t)b * DD * EE;
  f32x4 acc[4][4];
  f32x4 z = {0.f, 0.f, 0.f, 0.f};
#pragma unroll
  for (int i = 0; i < 4; ++i)
#pragma unroll
    for (int j = 0; j < 4; ++j) acc[i][j] = z;
  for (int kk = 0; kk < EE; kk += 32) {
#pragma unroll
    for (int q = 0; q < 2; ++q) {
      int rr = (q * 4 + w) * 16 + rA;
      int lb = (q * 4 + w) * 512;
      gload16(w2thi + (size_t)(m0 + rr) * EE + kk + cA, smA + lb);
      gload16(Bh + (size_t)(n0 + rr) * EE + kk + cA, smB + lb);
    }
    __syncthreads();
    f16x8 ah[4], bh[4];
#pragma unroll
    for (int i = 0; i < 4; ++i) {
      ah[i] = *(const f16x8*)&smA[(wm * 64 + i * 16 + lr) * 32 + lq];
      bh[i] = *(const f16x8*)&smB[(wn * 64 + i * 16 + lr) * 32 + lq];
    }
#pragma unroll
    for (int i = 0; i < 4; ++i)
#pragma unroll
      for (int j = 0; j < 4; ++j)
        acc[i][j] = __builtin_amdgcn_mfma_f32_16x16x32_f16(ah[i], bh[j], acc[i][j], 0, 0, 0);
    __syncthreads();
  }
#pragma unroll
  for (int i = 0; i < 4; ++i)
#pragma unroll
    for (int j = 0; j < 4; ++j) {
      int e = m0 + wm * 64 + i * 16 + (l >> 4) * 4;
      int d = n0 + wn * 64 + j * 16 + lr;
      f16x4 v16;
#pragma unroll
      for (int r = 0; r < 4; ++r) {
        out1[((size_t)b * EE + e + r) * DD + d] = acc[i][j][r];
        v16[r] = (_Float16)acc[i][j][r];
      }
      *(f16x4*)&out1T[((size_t)b * DD + d) * EE + e] = v16;
    }
}

// node_sc[b,n] = sum_d h[b,n,d]*a[d]
__global__ __launch_bounds__(256) void k_d1(const float* __restrict__ h, const float* __restrict__ a,
                                            float* __restrict__ node_sc) {
  int t = threadIdx.x;
  int w = t >> 6, l = t & 63;
  int row = blockIdx.x * 4 + w;
  float4 hv = *(const float4*)&h[(size_t)row * DD + l * 4];
  float4 av = *(const float4*)&a[l * 4];
  float s = hv.x * av.x + hv.y * av.y + hv.z * av.z + hv.w * av.w;
#pragma unroll
  for (int off = 32; off > 0; off >>= 1) s += __shfl_down(s, off);
  if (l == 0) node_sc[row] = s;
}

// att16[b,n,e] = softmax coefficient (fp16), computed from stats
__global__ __launch_bounds__(256) void k_att(const float* __restrict__ inc, const float* __restrict__ node_sc,
                                             const float* __restrict__ edge_sc, const float* __restrict__ time_e,
                                             const float* __restrict__ rmax, const float* __restrict__ rinv,
                                             const float* __restrict__ a3, _Float16* __restrict__ att16) {
  int n = blockIdx.x, b = blockIdx.y;
  int e = threadIdx.x * 4;
  float a30 = a3[0], a31 = a3[1];
  float ns = node_sc[b * NN + n];
  float4 icv = *(const float4*)&inc[(size_t)n * EE + e];
  int be = b * EE + e;
  float4 esc = *(const float4*)&edge_sc[be];
  float4 te = *(const float4*)&time_e[be];
  float4 rm = *(const float4*)&rmax[be];
  float4 ri = *(const float4*)&rinv[be];
  float ica[4] = {icv.x, icv.y, icv.z, icv.w};
  float ea[4] = {esc.x, esc.y, esc.z, esc.w};
  float ta[4] = {te.x, te.y, te.z, te.w};
  float ma[4] = {rm.x, rm.y, rm.z, rm.w};
  float ra[4] = {ri.x, ri.y, ri.z, ri.w};
  f16x4 o;
#pragma unroll
  for (int q = 0; q < 4; ++q) {
    float att = 0.f;
    if (ica[q] > 0.f) {
      float s1 = lrelu(ns + ea[q]);
      float s2 = lrelu(ta[q] * a30 + s1 * a31);
      att = __expf(s2 - ma[q]) * ra[q];
    }
    o[q] = (_Float16)att;
  }
  *(f16x4*)&att16[((size_t)b * NN + n) * EE + e] = o;
}

// out0[b,d,n] = sum_e att16[n,e]*out1T16[d,e]; fp16 MFMA, swizzled LDS
__global__ __launch_bounds__(256) void k_fgemm(const _Float16* __restrict__ att16, const _Float16* __restrict__ out1T,
                                               float* __restrict__ out0) {
  __shared__ _Float16 smA[64 * 64];
  __shared__ _Float16 smB[64 * 64];
  int b = blockIdx.z;
  int n0 = blockIdx.x * 64, d0 = blockIdx.y * 64;
  int t = threadIdx.x, w = t >> 6, l = t & 63;
  int wm = w >> 1, wn = w & 1;
  int lr = l & 15;
  const _Float16* A = att16 + ((size_t)b * NN + n0) * EE;
  const _Float16* Bp = out1T + ((size_t)b * DD + d0) * EE;
  int lrow = l >> 3;                      // 0..7 within the 8-row chunk
  int scol = 8 * ((l & 7) ^ (lrow & 7));  // pre-swizzled source column (f16 elems)
  f32x4 acc[2][2];
  f32x4 z = {0.f, 0.f, 0.f, 0.f};
#pragma unroll
  for (int i = 0; i < 2; ++i)
#pragma unroll
    for (int j = 0; j < 2; ++j) acc[i][j] = z;
  for (int kk = 0; kk < EE; kk += 64) {
#pragma unroll
    for (int q = 0; q < 2; ++q) {
      int row = q * 32 + w * 8 + lrow;
      int lb = (q * 32 + w * 8) * 64;  // f16 elems; lane adds 16B*l
      gload16(A + (size_t)row * EE + kk + scol, smA + lb);
      gload16(Bp + (size_t)row * EE + kk + scol, smB + lb);
    }
    __syncthreads();
    f16x8 af[2][2], bf[2][2];
#pragma unroll
    for (int i = 0; i < 2; ++i)
#pragma unroll
      for (int ks = 0; ks < 2; ++ks) {
        int ra = wm * 32 + i * 16 + lr;
        af[i][ks] = *(const f16x8*)&smA[ra * 64 + ((ks * 32 + (l >> 4) * 8) ^ ((ra & 7) << 3))];
        int rb = wn * 32 + i * 16 + lr;
        bf[i][ks] = *(const f16x8*)&smB[rb * 64 + ((ks * 32 + (l >> 4) * 8) ^ ((rb & 7) << 3))];
      }
#pragma unroll
    for (int ks = 0; ks < 2; ++ks)
#pragma unroll
      for (int i = 0; i < 2; ++i)
#pragma unroll
        for (int j = 0; j < 2; ++j)
          acc[i][j] = __builtin_amdgcn_mfma_f32_16x16x32_f16(af[i][ks], bf[j][ks], acc[i][j], 0, 0, 0);
    __syncthreads();
  }
  float* ob = out0 + (size_t)b * DD * NN;
#pragma unroll
  for (int i = 0; i < 2; ++i)
#pragma unroll
    for (int j = 0; j < 2; ++j) {
      int n = n0 + wm * 32 + i * 16 + (l >> 4) * 4;
      int d = d0 + wn * 32 + j * 16 + lr;
      *(float4*)&ob[(size_t)d * NN + n] =
          make_float4(acc[i][j][0], acc[i][j][1], acc[i][j][2], acc[i][j][3]);
    }
}

extern "C" void kernel_launch(void* const* d_in, const int* in_sizes, int n_in, void* d_out, int out_size,
                              void* d_ws, size_t ws_size, hipStream_t stream) {
  (void)in_sizes;
  (void)n_in;
  (void)out_size;
  (void)ws_size;
  const float* x = (const float*)d_in[0];
  const float* m = (const float*)d_in[1];
  const float* hid = (const float*)d_in[2];
  const float* pri_e = (const float*)d_in[3];
  const float* inc = (const float*)d_in[5];
  const float* W = (const float*)d_in[6];
  const float* bias = (const float*)d_in[7];
  const float* W2 = (const float*)d_in[8];
  const float* a = (const float*)d_in[9];
  const float* a2 = (const float*)d_in[10];
  const float* a3 = (const float*)d_in[11];

  float* out0 = (float*)d_out;                // [B,D,N]; h fp32 scratch until k_fgemm
  float* out1 = out0 + (size_t)BB * DD * NN;  // [B,E,D] fp32
  float* h = out0;
  _Float16* hThi = (_Float16*)out1;  // [B,D,N] fp16 (dead after k_edge1; k_out1 overwrites)
  _Float16* hTlo = hThi + (size_t)BB * DD * NN;

  _Float16* e1hi = (_Float16*)d_ws;              // [B,D,E]
  _Float16* e1lo = e1hi + (size_t)BB * DD * EE;  // [B,D,E]
  _Float16* att16 = e1hi;                        // alias: written after e1hi dead (post k_out1)
  _Float16* out1T16 = e1lo;                      // alias: written after e1lo dead (post k_u)
  _Float16* incT = e1lo + (size_t)BB * DD * EE;  // [E,N]
  _Float16* w2thi = incT + (size_t)EE * NN;      // [E,E]
  float* invdeg = (float*)(w2thi + (size_t)EE * EE);  // E
  float* node_sc = invdeg + EE;                       // B*N
  float* edge_sc = node_sc + (size_t)BB * NN;         // B*E
  float* time_e = edge_sc + (size_t)BB * EE;          // B*E
  float* rmax = time_e + (size_t)BB * EE;             // B*E
  float* rinv = rmax + (size_t)BB * EE;               // B*E
  float* u1 = rinv + (size_t)BB * EE;                 // B*E
  float* u2 = u1 + (size_t)BB * EE;                   // B*E

  k_deg<<<dim3(EE / 256), 256, 0, stream>>>(inc, invdeg);
  k_incT<<<dim3(EE / 64, NN / 64), 256, 0, stream>>>(inc, incT);
  k_w2t<<<dim3(EE / 64, EE / 64), 256, 0, stream>>>(W2, w2thi);
  k_h<<<dim3(DD / 64, NN / 64, BB), 256, 0, stream>>>(x, m, hid, W, bias, h, hThi, hTlo);
  k_d1<<<dim3((BB * NN) / 4), 256, 0, stream>>>(h, a, node_sc);
  k_edge1<<<dim3(EE / 128, DD / 128, BB), 256, 0, stream>>>(incT, hThi, hTlo, invdeg, e1hi, e1lo);
  k_u<<<dim3(EE / 64, BB), 256, 0, stream>>>(e1hi, e1lo, a, a2, u1, u2);
  k_esc<<<dim3(EE / 64, BB), 256, 0, stream>>>(W2, u1, u2, pri_e, a2, edge_sc, time_e);
  k_d3<<<dim3((BB * EE) / 4), 256, 0, stream>>>(incT, node_sc, edge_sc, time_e, a3, rmax, rinv);
  k_out1<<<dim3(EE / 128, DD / 128, BB), 256, 0, stream>>>(w2thi, e1hi, out1, out1T16);
  k_att<<<dim3(NN, BB), 256, 0, stream>>>(inc, node_sc, edge_sc, time_e, rmax, rinv, a3, att16);
  k_fgemm<<<dim3(NN / 64, DD / 64, BB), 256, 0, stream>>>(att16, out1T16, out0);
}

// Round 5
// 216.045 us; speedup vs baseline: 2.9740x; 1.0664x over previous
//
#include <hip/hip_runtime.h>

#define BB 48
#define NN 256
#define EE 1024
#define DD 256
#define CIN 256

typedef __attribute__((ext_vector_type(4))) float f32x4;
typedef __attribute__((ext_vector_type(8))) _Float16 f16x8;
typedef __attribute__((ext_vector_type(4))) _Float16 f16x4;

__device__ __forceinline__ float lrelu(float t) { return t >= 0.0f ? t : 0.2f * t; }

__device__ __forceinline__ void gload16(const void* g, void* l) {
  __builtin_amdgcn_global_load_lds((const __attribute__((address_space(1))) void*)g,
                                   (__attribute__((address_space(3))) void*)l, 16, 0, 0);
}

// deg[e] = sum_n inc[n,e]; store 1/deg
__global__ __launch_bounds__(256) void k_deg(const float* __restrict__ inc, float* __restrict__ invdeg) {
  int e = blockIdx.x * 256 + threadIdx.x;
  float s = 0.f;
  for (int n = 0; n < NN; ++n) s += inc[(size_t)n * EE + e];
  invdeg[e] = 1.0f / s;
}

// incT[e,n] = inc[n,e]  (fp16, exact 0/1)
__global__ __launch_bounds__(256) void k_incT(const float* __restrict__ inc, _Float16* __restrict__ incT) {
  __shared__ float tile[64][65];
  int e0 = blockIdx.x * 64, n0 = blockIdx.y * 64;
  int t = threadIdx.x, c = t & 63, r = t >> 6;
#pragma unroll
  for (int i = 0; i < 16; ++i) tile[r + i * 4][c] = inc[(size_t)(n0 + r + i * 4) * EE + e0 + c];
  __syncthreads();
#pragma unroll
  for (int i = 0; i < 16; ++i) {
    int row = r + i * 4;
    incT[(size_t)(e0 + row) * NN + n0 + c] = (_Float16)tile[c][row];
  }
}

// w2t[e,f] = fp16(W2[f,e])
__global__ __launch_bounds__(256) void k_w2t(const float* __restrict__ W2, _Float16* __restrict__ hi) {
  __shared__ float tile[64][65];
  int f0 = blockIdx.x * 64, e0 = blockIdx.y * 64;
  int t = threadIdx.x, c = t & 63, r = t >> 6;
#pragma unroll
  for (int i = 0; i < 16; ++i) tile[r + i * 4][c] = W2[(size_t)(f0 + r + i * 4) * EE + e0 + c];
  __syncthreads();
#pragma unroll
  for (int i = 0; i < 16; ++i) {
    int row = r + i * 4;
    hi[(size_t)(e0 + row) * EE + f0 + c] = (_Float16)tile[c][row];
  }
}

// h = x_in^T W + bias[n]; emits hThi fp16 [b,d,n] and per-d-block partial dots (node_sc, g1, g2)
__global__ __launch_bounds__(256) void k_h(const float* __restrict__ x, const float* __restrict__ m,
                                           const float* __restrict__ hid, const float* __restrict__ W,
                                           const float* __restrict__ bias, const float* __restrict__ aa,
                                           const float* __restrict__ a2p, _Float16* __restrict__ hThi,
                                           float* __restrict__ part) {
  __shared__ float sa[16][68];
  __shared__ float sb[16][68];
  int b = blockIdx.z;
  int j0 = blockIdx.x * 64;  // d
  int i0 = blockIdx.y * 64;  // n
  int t = threadIdx.x;
  int tx = t & 15, ty = t >> 4;
  float acc[4][4] = {};
  for (int kk = 0; kk < CIN; kk += 16) {
    for (int r = 0; r < 4; ++r) {
      int idx = t + r * 256;
      int k = idx >> 6, i = idx & 63;
      int c = kk + k;
      const float* row;
      if (c < 96) row = x + ((size_t)b * 96 + c) * NN;
      else if (c < 192) row = m + ((size_t)b * 96 + (c - 96)) * NN;
      else row = hid + ((size_t)b * 64 + (c - 192)) * NN;
      sa[k][i] = row[i0 + i];
      sb[k][i] = W[(size_t)c * DD + j0 + i];
    }
    __syncthreads();
#pragma unroll
    for (int k = 0; k < 16; ++k) {
      float4 av = *(const float4*)&sa[k][ty * 4];
      float4 bv = *(const float4*)&sb[k][tx * 4];
      float ar[4] = {av.x, av.y, av.z, av.w};
      float br[4] = {bv.x, bv.y, bv.z, bv.w};
#pragma unroll
      for (int ii = 0; ii < 4; ++ii)
#pragma unroll
        for (int jj = 0; jj < 4; ++jj) acc[ii][jj] += ar[ii] * br[jj];
    }
    __syncthreads();
  }
  float vv[4][4];
#pragma unroll
  for (int ii = 0; ii < 4; ++ii) {
    float bv = bias[i0 + ty * 4 + ii];
#pragma unroll
    for (int jj = 0; jj < 4; ++jj) vv[ii][jj] = acc[ii][jj] + bv;
  }
  _Float16* thb = hThi + (size_t)b * DD * NN;
#pragma unroll
  for (int jj = 0; jj < 4; ++jj) {
    int d = j0 + tx * 4 + jj;
    f16x4 vh;
#pragma unroll
    for (int ii = 0; ii < 4; ++ii) vh[ii] = (_Float16)vv[ii][jj];
    *(f16x4*)&thb[(size_t)d * NN + i0 + ty * 4] = vh;
  }
  float4 a0 = *(const float4*)&aa[j0 + tx * 4];
  float4 a1 = *(const float4*)&aa[DD + j0 + tx * 4];
  float4 a2v = *(const float4*)&a2p[j0 + tx * 4];
#pragma unroll
  for (int ii = 0; ii < 4; ++ii) {
    float s0 = vv[ii][0] * a0.x + vv[ii][1] * a0.y + vv[ii][2] * a0.z + vv[ii][3] * a0.w;
    float s1 = vv[ii][0] * a1.x + vv[ii][1] * a1.y + vv[ii][2] * a1.z + vv[ii][3] * a1.w;
    float s2 = vv[ii][0] * a2v.x + vv[ii][1] * a2v.y + vv[ii][2] * a2v.z + vv[ii][3] * a2v.w;
#pragma unroll
    for (int off = 8; off > 0; off >>= 1) {
      s0 += __shfl_down(s0, off, 16);
      s1 += __shfl_down(s1, off, 16);
      s2 += __shfl_down(s2, off, 16);
    }
    if (tx == 0) {
      int n = i0 + ty * 4 + ii;
      size_t pb = ((size_t)((j0 >> 6) * BB + b) * NN + n) * 3;
      part[pb] = s0;
      part[pb + 1] = s1;
      part[pb + 2] = s2;
    }
  }
}

// reduce 4 d-block partials -> node_sc, g1, g2
__global__ __launch_bounds__(256) void k_nred(const float* __restrict__ part, float* __restrict__ node_sc,
                                              float* __restrict__ g1, float* __restrict__ g2) {
  int idx = blockIdx.x * 256 + threadIdx.x;  // b*N+n
  float s0 = 0.f, s1 = 0.f, s2 = 0.f;
#pragma unroll
  for (int q = 0; q < 4; ++q) {
    size_t pb = ((size_t)q * BB * NN + idx) * 3;
    s0 += part[pb];
    s1 += part[pb + 1];
    s2 += part[pb + 2];
  }
  node_sc[idx] = s0;
  g1[idx] = s1;
  g2[idx] = s2;
}

// u1[b,f] = invdeg[f]*sum_n incT[f,n]*g1[b,n];  u2 same with g2   (exact fp32)
__global__ __launch_bounds__(256) void k_uu(const _Float16* __restrict__ incT, const float* __restrict__ g1,
                                            const float* __restrict__ g2, const float* __restrict__ invdeg,
                                            float* __restrict__ u1, float* __restrict__ u2) {
  __shared__ float sg1[NN], sg2[NN];
  __shared__ float r1[4][64], r2[4][64];
  int b = blockIdx.y;
  int f0 = blockIdx.x * 64;
  int t = threadIdx.x;
  sg1[t] = g1[b * NN + t];
  sg2[t] = g2[b * NN + t];
  __syncthreads();
  int fl = t & 63, ng = t >> 6;
  int f = f0 + fl;
  float s1 = 0.f, s2 = 0.f;
  const _Float16* row = incT + (size_t)f * NN + ng * 64;
  for (int i = 0; i < 64; i += 8) {
    f16x8 ic = *(const f16x8*)&row[i];
#pragma unroll
    for (int j = 0; j < 8; ++j) {
      float icf = (float)ic[j];
      int n = ng * 64 + i + j;
      s1 += icf * sg1[n];
      s2 += icf * sg2[n];
    }
  }
  r1[ng][fl] = s1;
  r2[ng][fl] = s2;
  __syncthreads();
  if (t < 64) {
    float iv = invdeg[f0 + t];
    u1[(size_t)b * EE + f0 + t] = (r1[0][t] + r1[1][t] + r1[2][t] + r1[3][t]) * iv;
    u2[(size_t)b * EE + f0 + t] = (r2[0][t] + r2[1][t] + r2[2][t] + r2[3][t]) * iv;
  }
}

// edge_sc[b,e] = sum_f W2[f,e]*u1[b,f];  time_e = lrelu(sum_f W2[f,e]*u2[b,f] + pri_e*a2[D]); 6 b per block
__global__ __launch_bounds__(256) void k_esc(const float* __restrict__ W2, const float* __restrict__ u1,
                                             const float* __restrict__ u2, const float* __restrict__ pri_e,
                                             const float* __restrict__ a2, float* __restrict__ edge_sc,
                                             float* __restrict__ time_e) {
  __shared__ float su1[6 * 1024];
  __shared__ float su2[6 * 1024];
  __shared__ float rr[2][4][6][64];
  int e0 = blockIdx.x * 64, b0 = blockIdx.y * 6;
  int t = threadIdx.x;
#pragma unroll
  for (int i = 0; i < 6; ++i) {
    *(float4*)&su1[i * 1024 + t * 4] = *(const float4*)&u1[(size_t)(b0 + i) * EE + t * 4];
    *(float4*)&su2[i * 1024 + t * 4] = *(const float4*)&u2[(size_t)(b0 + i) * EE + t * 4];
  }
  __syncthreads();
  int el = t & 63, fg = t >> 6;
  int e = e0 + el;
  float s1[6] = {}, s2[6] = {};
  for (int i = 0; i < 256; i += 4) {
    int f = fg * 256 + i;
    float w0 = W2[(size_t)f * EE + e];
    float w1 = W2[(size_t)(f + 1) * EE + e];
    float w2v = W2[(size_t)(f + 2) * EE + e];
    float w3 = W2[(size_t)(f + 3) * EE + e];
#pragma unroll
    for (int bl = 0; bl < 6; ++bl) {
      f32x4 va = *(const f32x4*)&su1[bl * 1024 + f];
      f32x4 vb = *(const f32x4*)&su2[bl * 1024 + f];
      s1[bl] += w0 * va[0] + w1 * va[1] + w2v * va[2] + w3 * va[3];
      s2[bl] += w0 * vb[0] + w1 * vb[1] + w2v * vb[2] + w3 * vb[3];
    }
  }
#pragma unroll
  for (int bl = 0; bl < 6; ++bl) {
    rr[0][fg][bl][el] = s1[bl];
    rr[1][fg][bl][el] = s2[bl];
  }
  __syncthreads();
  for (int bl = t >> 6; bl < 6; bl += 4) {
    int ee = t & 63;
    int row = (b0 + bl) * EE + e0 + ee;
    float v1 = rr[0][0][bl][ee] + rr[0][1][bl][ee] + rr[0][2][bl][ee] + rr[0][3][bl][ee];
    float v2 = rr[1][0][bl][ee] + rr[1][1][bl][ee] + rr[1][2][bl][ee] + rr[1][3][bl][ee];
    edge_sc[row] = v1;
    time_e[row] = lrelu(v2 + pri_e[row] * a2[DD]);
  }
}

// softmax stats over n per (b,e)
__global__ __launch_bounds__(256) void k_d3(const _Float16* __restrict__ incT, const float* __restrict__ node_sc,
                                            const float* __restrict__ edge_sc, const float* __restrict__ time_e,
                                            const float* __restrict__ a3, float* __restrict__ rmax,
                                            float* __restrict__ rinv) {
  int t = threadIdx.x;
  int w = t >> 6, l = t & 63;
  int row = blockIdx.x * 4 + w;
  int b = row >> 10;
  int e = row & (EE - 1);
  float a30 = a3[0], a31 = a3[1];
  float esc = edge_sc[row], te = time_e[row];
  float s2v[4];
  bool msk[4];
  float vmax = -3.0e38f;
#pragma unroll
  for (int q = 0; q < 4; ++q) {
    int n = l + q * 64;
    float ic = (float)incT[(size_t)e * NN + n];
    float s1 = lrelu(node_sc[(size_t)b * NN + n] + esc);
    float s2 = lrelu(te * a30 + s1 * a31);
    msk[q] = ic > 0.f;
    s2v[q] = s2;
    if (msk[q]) vmax = fmaxf(vmax, s2);
  }
#pragma unroll
  for (int off = 32; off > 0; off >>= 1) vmax = fmaxf(vmax, __shfl_xor(vmax, off));
  float ss = 0.f;
#pragma unroll
  for (int q = 0; q < 4; ++q)
    if (msk[q]) ss += __expf(s2v[q] - vmax);
#pragma unroll
  for (int off = 32; off > 0; off >>= 1) ss += __shfl_xor(ss, off);
  if (l == 0) {
    rmax[row] = vmax;
    rinv[row] = 1.0f / ss;
  }
}

// e1[b,d,e] = (sum_n hT[d,n]*incT[e,n]) * invdeg[e]; 1-term MFMA, BK=64, XOR-swizzled LDS
__global__ __launch_bounds__(256) void k_edge1(const _Float16* __restrict__ incT, const _Float16* __restrict__ hThi,
                                               const float* __restrict__ invdeg, _Float16* __restrict__ e1) {
  __shared__ _Float16 smA[128 * 64];
  __shared__ _Float16 smB[128 * 64];
  int b = blockIdx.z;
  int m0 = blockIdx.x * 128;  // e
  int n0 = blockIdx.y * 128;  // d
  int t = threadIdx.x, w = t >> 6, l = t & 63;
  int wm = w >> 1, wn = w & 1;
  int lr = l & 15, lg = l >> 4;
  int srow = l >> 3, sgrp = l & 7;
  const _Float16* A = incT + (size_t)m0 * NN;
  const _Float16* Bp = hThi + ((size_t)b * DD + n0) * NN;
  f32x4 acc[4][4];
  f32x4 z = {0.f, 0.f, 0.f, 0.f};
#pragma unroll
  for (int i = 0; i < 4; ++i)
#pragma unroll
    for (int j = 0; j < 4; ++j) acc[i][j] = z;
  for (int kk = 0; kk < NN; kk += 64) {
#pragma unroll
    for (int q = 0; q < 4; ++q) {
      int c = w * 4 + q;
      int r = c * 8 + srow;
      int sc = (sgrp ^ (r & 7)) * 8;
      gload16(A + (size_t)r * NN + kk + sc, smA + c * 512);
      gload16(Bp + (size_t)r * NN + kk + sc, smB + c * 512);
    }
    __syncthreads();
    f16x8 ah[4][2], bh[4][2];
#pragma unroll
    for (int i = 0; i < 4; ++i) {
      int ra = wm * 64 + i * 16 + lr;
      int rb = wn * 64 + i * 16 + lr;
#pragma unroll
      for (int ks = 0; ks < 2; ++ks) {
        ah[i][ks] = *(const f16x8*)&smA[ra * 64 + (((ks * 4 + lg) ^ (ra & 7)) * 8)];
        bh[i][ks] = *(const f16x8*)&smB[rb * 64 + (((ks * 4 + lg) ^ (rb & 7)) * 8)];
      }
    }
#pragma unroll
    for (int ks = 0; ks < 2; ++ks)
#pragma unroll
      for (int i = 0; i < 4; ++i)
#pragma unroll
        for (int j = 0; j < 4; ++j)
          acc[i][j] = __builtin_amdgcn_mfma_f32_16x16x32_f16(ah[i][ks], bh[j][ks], acc[i][j], 0, 0, 0);
    __syncthreads();
  }
#pragma unroll
  for (int i = 0; i < 4; ++i)
#pragma unroll
    for (int j = 0; j < 4; ++j) {
      int e = m0 + wm * 64 + i * 16 + lg * 4;
      int d = n0 + wn * 64 + j * 16 + lr;
      f16x4 vh;
#pragma unroll
      for (int r = 0; r < 4; ++r) vh[r] = (_Float16)(acc[i][j][r] * invdeg[e + r]);
      *(f16x4*)&e1[((size_t)b * DD + d) * EE + e] = vh;
    }
}

// out1[b,e,d] = sum_f w2t[e,f]*e1[d,f]; fp16 MFMA BK=64 swizzled; XCD-pinned grid; emits out1T16
__global__ __launch_bounds__(256) void k_out1(const _Float16* __restrict__ w2t, const _Float16* __restrict__ e1,
                                              float* __restrict__ out1, _Float16* __restrict__ out1T) {
  __shared__ _Float16 smA[128 * 64];
  __shared__ _Float16 smB[128 * 64];
  int bid = blockIdx.x;
  int m0 = (bid & 7) * 128;         // e-panel: constant per XCD -> w2t panel L2-resident
  int n0 = ((bid >> 3) & 1) * 128;  // d
  int b = bid >> 4;
  int t = threadIdx.x, w = t >> 6, l = t & 63;
  int wm = w >> 1, wn = w & 1;
  int lr = l & 15, lg = l >> 4;
  int srow = l >> 3, sgrp = l & 7;
  const _Float16* A = w2t + (size_t)m0 * EE;
  const _Float16* Bp = e1 + ((size_t)b * DD + n0) * EE;
  f32x4 acc[4][4];
  f32x4 z = {0.f, 0.f, 0.f, 0.f};
#pragma unroll
  for (int i = 0; i < 4; ++i)
#pragma unroll
    for (int j = 0; j < 4; ++j) acc[i][j] = z;
  for (int kk = 0; kk < EE; kk += 64) {
#pragma unroll
    for (int q = 0; q < 4; ++q) {
      int c = w * 4 + q;
      int r = c * 8 + srow;
      int sc = (sgrp ^ (r & 7)) * 8;
      gload16(A + (size_t)r * EE + kk + sc, smA + c * 512);
      gload16(Bp + (size_t)r * EE + kk + sc, smB + c * 512);
    }
    __syncthreads();
    f16x8 ah[4][2], bh[4][2];
#pragma unroll
    for (int i = 0; i < 4; ++i) {
      int ra = wm * 64 + i * 16 + lr;
      int rb = wn * 64 + i * 16 + lr;
#pragma unroll
      for (int ks = 0; ks < 2; ++ks) {
        ah[i][ks] = *(const f16x8*)&smA[ra * 64 + (((ks * 4 + lg) ^ (ra & 7)) * 8)];
        bh[i][ks] = *(const f16x8*)&smB[rb * 64 + (((ks * 4 + lg) ^ (rb & 7)) * 8)];
      }
    }
#pragma unroll
    for (int ks = 0; ks < 2; ++ks)
#pragma unroll
      for (int i = 0; i < 4; ++i)
#pragma unroll
        for (int j = 0; j < 4; ++j)
          acc[i][j] = __builtin_amdgcn_mfma_f32_16x16x32_f16(ah[i][ks], bh[j][ks], acc[i][j], 0, 0, 0);
    __syncthreads();
  }
#pragma unroll
  for (int i = 0; i < 4; ++i)
#pragma unroll
    for (int j = 0; j < 4; ++j) {
      int e = m0 + wm * 64 + i * 16 + lg * 4;
      int d = n0 + wn * 64 + j * 16 + lr;
      f16x4 v16;
#pragma unroll
      for (int r = 0; r < 4; ++r) {
        out1[((size_t)b * EE + e + r) * DD + d] = acc[i][j][r];
        v16[r] = (_Float16)acc[i][j][r];
      }
      *(f16x4*)&out1T[((size_t)b * DD + d) * EE + e] = v16;
    }
}

// att16[b,n,e] = softmax coefficient (fp16)
__global__ __launch_bounds__(256) void k_att(const float* __restrict__ inc, const float* __restrict__ node_sc,
                                             const float* __restrict__ edge_sc, const float* __restrict__ time_e,
                                             const float* __restrict__ rmax, const float* __restrict__ rinv,
                                             const float* __restrict__ a3, _Float16* __restrict__ att16) {
  int n = blockIdx.x, b = blockIdx.y;
  int e = threadIdx.x * 4;
  float a30 = a3[0], a31 = a3[1];
  float ns = node_sc[b * NN + n];
  float4 icv = *(const float4*)&inc[(size_t)n * EE + e];
  int be = b * EE + e;
  float4 esc = *(const float4*)&edge_sc[be];
  float4 te = *(const float4*)&time_e[be];
  float4 rm = *(const float4*)&rmax[be];
  float4 ri = *(const float4*)&rinv[be];
  float ica[4] = {icv.x, icv.y, icv.z, icv.w};
  float ea[4] = {esc.x, esc.y, esc.z, esc.w};
  float ta[4] = {te.x, te.y, te.z, te.w};
  float ma[4] = {rm.x, rm.y, rm.z, rm.w};
  float ra[4] = {ri.x, ri.y, ri.z, ri.w};
  f16x4 o;
#pragma unroll
  for (int q = 0; q < 4; ++q) {
    float att = 0.f;
    if (ica[q] > 0.f) {
      float s1 = lrelu(ns + ea[q]);
      float s2 = lrelu(ta[q] * a30 + s1 * a31);
      att = __expf(s2 - ma[q]) * ra[q];
    }
    o[q] = (_Float16)att;
  }
  *(f16x4*)&att16[((size_t)b * NN + n) * EE + e] = o;
}

// out0[b,d,n] = sum_e att16[n,e]*out1T16[d,e]; fp16 MFMA, swizzled LDS
__global__ __launch_bounds__(256) void k_fgemm(const _Float16* __restrict__ att16, const _Float16* __restrict__ out1T,
                                               float* __restrict__ out0) {
  __shared__ _Float16 smA[64 * 64];
  __shared__ _Float16 smB[64 * 64];
  int b = blockIdx.z;
  int n0 = blockIdx.x * 64, d0 = blockIdx.y * 64;
  int t = threadIdx.x, w = t >> 6, l = t & 63;
  int wm = w >> 1, wn = w & 1;
  int lr = l & 15;
  const _Float16* A = att16 + ((size_t)b * NN + n0) * EE;
  const _Float16* Bp = out1T + ((size_t)b * DD + d0) * EE;
  int lrow = l >> 3;
  int scol = 8 * ((l & 7) ^ (lrow & 7));
  f32x4 acc[2][2];
  f32x4 z = {0.f, 0.f, 0.f, 0.f};
#pragma unroll
  for (int i = 0; i < 2; ++i)
#pragma unroll
    for (int j = 0; j < 2; ++j) acc[i][j] = z;
  for (int kk = 0; kk < EE; kk += 64) {
#pragma unroll
    for (int q = 0; q < 2; ++q) {
      int row = q * 32 + w * 8 + lrow;
      int lb = (q * 32 + w * 8) * 64;
      gload16(A + (size_t)row * EE + kk + scol, smA + lb);
      gload16(Bp + (size_t)row * EE + kk + scol, smB + lb);
    }
    __syncthreads();
    f16x8 af[2][2], bf[2][2];
#pragma unroll
    for (int i = 0; i < 2; ++i)
#pragma unroll
      for (int ks = 0; ks < 2; ++ks) {
        int ra = wm * 32 + i * 16 + lr;
        af[i][ks] = *(const f16x8*)&smA[ra * 64 + ((ks * 32 + (l >> 4) * 8) ^ ((ra & 7) << 3))];
        int rb = wn * 32 + i * 16 + lr;
        bf[i][ks] = *(const f16x8*)&smB[rb * 64 + ((ks * 32 + (l >> 4) * 8) ^ ((rb & 7) << 3))];
      }
#pragma unroll
    for (int ks = 0; ks < 2; ++ks)
#pragma unroll
      for (int i = 0; i < 2; ++i)
#pragma unroll
        for (int j = 0; j < 2; ++j)
          acc[i][j] = __builtin_amdgcn_mfma_f32_16x16x32_f16(af[i][ks], bf[j][ks], acc[i][j], 0, 0, 0);
    __syncthreads();
  }
  float* ob = out0 + (size_t)b * DD * NN;
#pragma unroll
  for (int i = 0; i < 2; ++i)
#pragma unroll
    for (int j = 0; j < 2; ++j) {
      int n = n0 + wm * 32 + i * 16 + (l >> 4) * 4;
      int d = d0 + wn * 32 + j * 16 + lr;
      *(float4*)&ob[(size_t)d * NN + n] =
          make_float4(acc[i][j][0], acc[i][j][1], acc[i][j][2], acc[i][j][3]);
    }
}

extern "C" void kernel_launch(void* const* d_in, const int* in_sizes, int n_in, void* d_out, int out_size,
                              void* d_ws, size_t ws_size, hipStream_t stream) {
  (void)in_sizes;
  (void)n_in;
  (void)out_size;
  (void)ws_size;
  const float* x = (const float*)d_in[0];
  const float* m = (const float*)d_in[1];
  const float* hid = (const float*)d_in[2];
  const float* pri_e = (const float*)d_in[3];
  const float* inc = (const float*)d_in[5];
  const float* W = (const float*)d_in[6];
  const float* bias = (const float*)d_in[7];
  const float* W2 = (const float*)d_in[8];
  const float* a = (const float*)d_in[9];
  const float* a2 = (const float*)d_in[10];
  const float* a3 = (const float*)d_in[11];

  float* out0 = (float*)d_out;                // [B,D,N]
  float* out1 = out0 + (size_t)BB * DD * NN;  // [B,E,D] fp32
  _Float16* hThi = (_Float16*)out1;           // [B,D,N] fp16 (dead before k_out1 writes out1)

  _Float16* e1 = (_Float16*)d_ws;                // [B,D,E] fp16; att16 aliases after k_out1
  _Float16* att16 = e1;
  _Float16* out1T16 = e1 + (size_t)BB * DD * EE;      // [B,D,E] fp16
  _Float16* incT = out1T16 + (size_t)BB * DD * EE;    // [E,N]
  _Float16* w2thi = incT + (size_t)EE * NN;           // [E,E]
  float* invdeg = (float*)(w2thi + (size_t)EE * EE);  // E
  float* node_sc = invdeg + EE;                       // B*N
  float* g1 = node_sc + (size_t)BB * NN;              // B*N
  float* g2 = g1 + (size_t)BB * NN;                   // B*N
  float* edge_sc = g2 + (size_t)BB * NN;              // B*E
  float* time_e = edge_sc + (size_t)BB * EE;          // B*E
  float* rmax = time_e + (size_t)BB * EE;             // B*E
  float* rinv = rmax + (size_t)BB * EE;               // B*E
  float* u1 = rinv + (size_t)BB * EE;                 // B*E
  float* u2 = u1 + (size_t)BB * EE;                   // B*E
  float* part = u2 + (size_t)BB * EE;                 // 4*B*N*3

  k_deg<<<dim3(EE / 256), 256, 0, stream>>>(inc, invdeg);
  k_incT<<<dim3(EE / 64, NN / 64), 256, 0, stream>>>(inc, incT);
  k_w2t<<<dim3(EE / 64, EE / 64), 256, 0, stream>>>(W2, w2thi);
  k_h<<<dim3(DD / 64, NN / 64, BB), 256, 0, stream>>>(x, m, hid, W, bias, a, a2, hThi, part);
  k_nred<<<dim3((BB * NN) / 256), 256, 0, stream>>>(part, node_sc, g1, g2);
  k_uu<<<dim3(EE / 64, BB), 256, 0, stream>>>(incT, g1, g2, invdeg, u1, u2);
  k_esc<<<dim3(EE / 64, BB / 6), 256, 0, stream>>>(W2, u1, u2, pri_e, a2, edge_sc, time_e);
  k_d3<<<dim3((BB * EE) / 4), 256, 0, stream>>>(incT, node_sc, edge_sc, time_e, a3, rmax, rinv);
  k_edge1<<<dim3(EE / 128, DD / 128, BB), 256, 0, stream>>>(incT, hThi, invdeg, e1);
  k_out1<<<dim3(8 * 2 * BB), 256, 0, stream>>>(w2thi, e1, out1, out1T16);
  k_att<<<dim3(NN, BB), 256, 0, stream>>>(inc, node_sc, edge_sc, time_e, rmax, rinv, a3, att16);
  k_fgemm<<<dim3(NN / 64, DD / 64, BB), 256, 0, stream>>>(att16, out1T16, out0);
}

// Round 6
// 191.340 us; speedup vs baseline: 3.3580x; 1.1291x over previous
//
#include <hip/hip_runtime.h>

#define BB 48
#define NN 256
#define EE 1024
#define DD 256
#define CIN 256

typedef __attribute__((ext_vector_type(4))) float f32x4;
typedef __attribute__((ext_vector_type(8))) _Float16 f16x8;
typedef __attribute__((ext_vector_type(4))) _Float16 f16x4;

__device__ __forceinline__ float lrelu(float t) { return t >= 0.0f ? t : 0.2f * t; }

__device__ __forceinline__ void gload16(const void* g, void* l) {
  __builtin_amdgcn_global_load_lds((const __attribute__((address_space(1))) void*)g,
                                   (__attribute__((address_space(3))) void*)l, 16, 0, 0);
}

// deg[e] = sum_n inc[n,e]; store 1/deg
__global__ __launch_bounds__(256) void k_deg(const float* __restrict__ inc, float* __restrict__ invdeg) {
  int e = blockIdx.x * 256 + threadIdx.x;
  float s = 0.f;
  for (int n = 0; n < NN; ++n) s += inc[(size_t)n * EE + e];
  invdeg[e] = 1.0f / s;
}

// incT[e,n] = inc[n,e]  (fp16, exact 0/1)
__global__ __launch_bounds__(256) void k_incT(const float* __restrict__ inc, _Float16* __restrict__ incT) {
  __shared__ float tile[64][65];
  int e0 = blockIdx.x * 64, n0 = blockIdx.y * 64;
  int t = threadIdx.x, c = t & 63, r = t >> 6;
#pragma unroll
  for (int i = 0; i < 16; ++i) tile[r + i * 4][c] = inc[(size_t)(n0 + r + i * 4) * EE + e0 + c];
  __syncthreads();
#pragma unroll
  for (int i = 0; i < 16; ++i) {
    int row = r + i * 4;
    incT[(size_t)(e0 + row) * NN + n0 + c] = (_Float16)tile[c][row];
  }
}

// w2t[e,f] = fp16(W2[f,e])
__global__ __launch_bounds__(256) void k_w2t(const float* __restrict__ W2, _Float16* __restrict__ hi) {
  __shared__ float tile[64][65];
  int f0 = blockIdx.x * 64, e0 = blockIdx.y * 64;
  int t = threadIdx.x, c = t & 63, r = t >> 6;
#pragma unroll
  for (int i = 0; i < 16; ++i) tile[r + i * 4][c] = W2[(size_t)(f0 + r + i * 4) * EE + e0 + c];
  __syncthreads();
#pragma unroll
  for (int i = 0; i < 16; ++i) {
    int row = r + i * 4;
    hi[(size_t)(e0 + row) * EE + f0 + c] = (_Float16)tile[c][row];
  }
}

// h = x_in^T W + bias[n]; emits hThi fp16 [b,d,n] and per-d-block partial dots (node_sc, g1, g2)
__global__ __launch_bounds__(256) void k_h(const float* __restrict__ x, const float* __restrict__ m,
                                           const float* __restrict__ hid, const float* __restrict__ W,
                                           const float* __restrict__ bias, const float* __restrict__ aa,
                                           const float* __restrict__ a2p, _Float16* __restrict__ hThi,
                                           float* __restrict__ part) {
  __shared__ float sa[16][68];
  __shared__ float sb[16][68];
  int b = blockIdx.z;
  int j0 = blockIdx.x * 64;  // d
  int i0 = blockIdx.y * 64;  // n
  int t = threadIdx.x;
  int tx = t & 15, ty = t >> 4;
  float acc[4][4] = {};
  for (int kk = 0; kk < CIN; kk += 16) {
    for (int r = 0; r < 4; ++r) {
      int idx = t + r * 256;
      int k = idx >> 6, i = idx & 63;
      int c = kk + k;
      const float* row;
      if (c < 96) row = x + ((size_t)b * 96 + c) * NN;
      else if (c < 192) row = m + ((size_t)b * 96 + (c - 96)) * NN;
      else row = hid + ((size_t)b * 64 + (c - 192)) * NN;
      sa[k][i] = row[i0 + i];
      sb[k][i] = W[(size_t)c * DD + j0 + i];
    }
    __syncthreads();
#pragma unroll
    for (int k = 0; k < 16; ++k) {
      float4 av = *(const float4*)&sa[k][ty * 4];
      float4 bv = *(const float4*)&sb[k][tx * 4];
      float ar[4] = {av.x, av.y, av.z, av.w};
      float br[4] = {bv.x, bv.y, bv.z, bv.w};
#pragma unroll
      for (int ii = 0; ii < 4; ++ii)
#pragma unroll
        for (int jj = 0; jj < 4; ++jj) acc[ii][jj] += ar[ii] * br[jj];
    }
    __syncthreads();
  }
  float vv[4][4];
#pragma unroll
  for (int ii = 0; ii < 4; ++ii) {
    float bv = bias[i0 + ty * 4 + ii];
#pragma unroll
    for (int jj = 0; jj < 4; ++jj) vv[ii][jj] = acc[ii][jj] + bv;
  }
  _Float16* thb = hThi + (size_t)b * DD * NN;
#pragma unroll
  for (int jj = 0; jj < 4; ++jj) {
    int d = j0 + tx * 4 + jj;
    f16x4 vh;
#pragma unroll
    for (int ii = 0; ii < 4; ++ii) vh[ii] = (_Float16)vv[ii][jj];
    *(f16x4*)&thb[(size_t)d * NN + i0 + ty * 4] = vh;
  }
  float4 a0 = *(const float4*)&aa[j0 + tx * 4];
  float4 a1 = *(const float4*)&aa[DD + j0 + tx * 4];
  float4 a2v = *(const float4*)&a2p[j0 + tx * 4];
#pragma unroll
  for (int ii = 0; ii < 4; ++ii) {
    float s0 = vv[ii][0] * a0.x + vv[ii][1] * a0.y + vv[ii][2] * a0.z + vv[ii][3] * a0.w;
    float s1 = vv[ii][0] * a1.x + vv[ii][1] * a1.y + vv[ii][2] * a1.z + vv[ii][3] * a1.w;
    float s2 = vv[ii][0] * a2v.x + vv[ii][1] * a2v.y + vv[ii][2] * a2v.z + vv[ii][3] * a2v.w;
#pragma unroll
    for (int off = 8; off > 0; off >>= 1) {
      s0 += __shfl_down(s0, off, 16);
      s1 += __shfl_down(s1, off, 16);
      s2 += __shfl_down(s2, off, 16);
    }
    if (tx == 0) {
      int n = i0 + ty * 4 + ii;
      size_t pb = ((size_t)((j0 >> 6) * BB + b) * NN + n) * 3;
      part[pb] = s0;
      part[pb + 1] = s1;
      part[pb + 2] = s2;
    }
  }
}

// reduce 4 d-block partials -> node_sc, g1, g2
__global__ __launch_bounds__(256) void k_nred(const float* __restrict__ part, float* __restrict__ node_sc,
                                              float* __restrict__ g1, float* __restrict__ g2) {
  int idx = blockIdx.x * 256 + threadIdx.x;  // b*N+n
  float s0 = 0.f, s1 = 0.f, s2 = 0.f;
#pragma unroll
  for (int q = 0; q < 4; ++q) {
    size_t pb = ((size_t)q * BB * NN + idx) * 3;
    s0 += part[pb];
    s1 += part[pb + 1];
    s2 += part[pb + 2];
  }
  node_sc[idx] = s0;
  g1[idx] = s1;
  g2[idx] = s2;
}

// u1[b,f] = invdeg[f]*sum_n incT[f,n]*g1[b,n];  u2 same with g2   (exact fp32)
__global__ __launch_bounds__(256) void k_uu(const _Float16* __restrict__ incT, const float* __restrict__ g1,
                                            const float* __restrict__ g2, const float* __restrict__ invdeg,
                                            float* __restrict__ u1, float* __restrict__ u2) {
  __shared__ float sg1[NN], sg2[NN];
  __shared__ float r1[4][64], r2[4][64];
  int b = blockIdx.y;
  int f0 = blockIdx.x * 64;
  int t = threadIdx.x;
  sg1[t] = g1[b * NN + t];
  sg2[t] = g2[b * NN + t];
  __syncthreads();
  int fl = t & 63, ng = t >> 6;
  int f = f0 + fl;
  float s1 = 0.f, s2 = 0.f;
  const _Float16* row = incT + (size_t)f * NN + ng * 64;
  for (int i = 0; i < 64; i += 8) {
    f16x8 ic = *(const f16x8*)&row[i];
#pragma unroll
    for (int j = 0; j < 8; ++j) {
      float icf = (float)ic[j];
      int n = ng * 64 + i + j;
      s1 += icf * sg1[n];
      s2 += icf * sg2[n];
    }
  }
  r1[ng][fl] = s1;
  r2[ng][fl] = s2;
  __syncthreads();
  if (t < 64) {
    float iv = invdeg[f0 + t];
    u1[(size_t)b * EE + f0 + t] = (r1[0][t] + r1[1][t] + r1[2][t] + r1[3][t]) * iv;
    u2[(size_t)b * EE + f0 + t] = (r2[0][t] + r2[1][t] + r2[2][t] + r2[3][t]) * iv;
  }
}

// edge_sc[b,e] = sum_f W2[f,e]*u1[b,f];  time_e = lrelu(... + pri_e*a2[D]); 6 b per block
__global__ __launch_bounds__(256) void k_esc(const float* __restrict__ W2, const float* __restrict__ u1,
                                             const float* __restrict__ u2, const float* __restrict__ pri_e,
                                             const float* __restrict__ a2, float* __restrict__ edge_sc,
                                             float* __restrict__ time_e) {
  __shared__ float su1[6 * 1024];
  __shared__ float su2[6 * 1024];
  __shared__ float rr[2][4][6][64];
  int e0 = blockIdx.x * 64, b0 = blockIdx.y * 6;
  int t = threadIdx.x;
#pragma unroll
  for (int i = 0; i < 6; ++i) {
    *(float4*)&su1[i * 1024 + t * 4] = *(const float4*)&u1[(size_t)(b0 + i) * EE + t * 4];
    *(float4*)&su2[i * 1024 + t * 4] = *(const float4*)&u2[(size_t)(b0 + i) * EE + t * 4];
  }
  __syncthreads();
  int el = t & 63, fg = t >> 6;
  int e = e0 + el;
  float s1[6] = {}, s2[6] = {};
  for (int i = 0; i < 256; i += 4) {
    int f = fg * 256 + i;
    float w0 = W2[(size_t)f * EE + e];
    float w1 = W2[(size_t)(f + 1) * EE + e];
    float w2v = W2[(size_t)(f + 2) * EE + e];
    float w3 = W2[(size_t)(f + 3) * EE + e];
#pragma unroll
    for (int bl = 0; bl < 6; ++bl) {
      f32x4 va = *(const f32x4*)&su1[bl * 1024 + f];
      f32x4 vb = *(const f32x4*)&su2[bl * 1024 + f];
      s1[bl] += w0 * va[0] + w1 * va[1] + w2v * va[2] + w3 * va[3];
      s2[bl] += w0 * vb[0] + w1 * vb[1] + w2v * vb[2] + w3 * vb[3];
    }
  }
#pragma unroll
  for (int bl = 0; bl < 6; ++bl) {
    rr[0][fg][bl][el] = s1[bl];
    rr[1][fg][bl][el] = s2[bl];
  }
  __syncthreads();
  for (int bl = t >> 6; bl < 6; bl += 4) {
    int ee = t & 63;
    int row = (b0 + bl) * EE + e0 + ee;
    float v1 = rr[0][0][bl][ee] + rr[0][1][bl][ee] + rr[0][2][bl][ee] + rr[0][3][bl][ee];
    float v2 = rr[1][0][bl][ee] + rr[1][1][bl][ee] + rr[1][2][bl][ee] + rr[1][3][bl][ee];
    edge_sc[row] = v1;
    time_e[row] = lrelu(v2 + pri_e[row] * a2[DD]);
  }
}

// softmax stats over n per (b,e)
__global__ __launch_bounds__(256) void k_d3(const _Float16* __restrict__ incT, const float* __restrict__ node_sc,
                                            const float* __restrict__ edge_sc, const float* __restrict__ time_e,
                                            const float* __restrict__ a3, float* __restrict__ rmax,
                                            float* __restrict__ rinv) {
  int t = threadIdx.x;
  int w = t >> 6, l = t & 63;
  int row = blockIdx.x * 4 + w;
  int b = row >> 10;
  int e = row & (EE - 1);
  float a30 = a3[0], a31 = a3[1];
  float esc = edge_sc[row], te = time_e[row];
  float s2v[4];
  bool msk[4];
  float vmax = -3.0e38f;
#pragma unroll
  for (int q = 0; q < 4; ++q) {
    int n = l + q * 64;
    float ic = (float)incT[(size_t)e * NN + n];
    float s1 = lrelu(node_sc[(size_t)b * NN + n] + esc);
    float s2 = lrelu(te * a30 + s1 * a31);
    msk[q] = ic > 0.f;
    s2v[q] = s2;
    if (msk[q]) vmax = fmaxf(vmax, s2);
  }
#pragma unroll
  for (int off = 32; off > 0; off >>= 1) vmax = fmaxf(vmax, __shfl_xor(vmax, off));
  float ss = 0.f;
#pragma unroll
  for (int q = 0; q < 4; ++q)
    if (msk[q]) ss += __expf(s2v[q] - vmax);
#pragma unroll
  for (int off = 32; off > 0; off >>= 1) ss += __shfl_xor(ss, off);
  if (l == 0) {
    rmax[row] = vmax;
    rinv[row] = 1.0f / ss;
  }
}

// e1[b,d,e] = (sum_n hT[d,n]*incT[e,n]) * invdeg[e]; 1-term MFMA, BK=64, XOR swizzle; b-pinned XCD
__global__ __launch_bounds__(256) void k_edge1(const _Float16* __restrict__ incT, const _Float16* __restrict__ hThi,
                                               const float* __restrict__ invdeg, _Float16* __restrict__ e1) {
  __shared__ _Float16 smA[128 * 64];
  __shared__ _Float16 smB[128 * 64];
  int bid = blockIdx.x;
  int xcd = bid & 7, il = bid >> 3;           // 96 per XCD
  int ep = il & 7, dblk = (il >> 3) & 1, bl = il >> 4;
  int b = xcd * 6 + bl;
  int m0 = ep * 128;   // e
  int n0 = dblk * 128; // d
  int t = threadIdx.x, w = t >> 6, l = t & 63;
  int wm = w >> 1, wn = w & 1;
  int lr = l & 15, lg = l >> 4;
  int srow = l >> 3, sgrp = l & 7;
  int sc = (sgrp ^ srow) * 8;
  const _Float16* A = incT + (size_t)m0 * NN;
  const _Float16* Bp = hThi + ((size_t)b * DD + n0) * NN;
  f32x4 acc[4][4];
  f32x4 z = {0.f, 0.f, 0.f, 0.f};
#pragma unroll
  for (int i = 0; i < 4; ++i)
#pragma unroll
    for (int j = 0; j < 4; ++j) acc[i][j] = z;
  for (int kk = 0; kk < NN; kk += 64) {
#pragma unroll
    for (int q = 0; q < 4; ++q) {
      int c = w * 4 + q;
      int r = c * 8 + srow;
      gload16(A + (size_t)r * NN + kk + sc, smA + c * 512);
      gload16(Bp + (size_t)r * NN + kk + sc, smB + c * 512);
    }
    __syncthreads();
    f16x8 ah[4][2], bh[4][2];
#pragma unroll
    for (int i = 0; i < 4; ++i) {
      int ra = wm * 64 + i * 16 + lr;
      int rb = wn * 64 + i * 16 + lr;
#pragma unroll
      for (int ks = 0; ks < 2; ++ks) {
        ah[i][ks] = *(const f16x8*)&smA[ra * 64 + (((ks * 4 + lg) ^ (ra & 7)) * 8)];
        bh[i][ks] = *(const f16x8*)&smB[rb * 64 + (((ks * 4 + lg) ^ (rb & 7)) * 8)];
      }
    }
#pragma unroll
    for (int ks = 0; ks < 2; ++ks)
#pragma unroll
      for (int i = 0; i < 4; ++i)
#pragma unroll
        for (int j = 0; j < 4; ++j)
          acc[i][j] = __builtin_amdgcn_mfma_f32_16x16x32_f16(ah[i][ks], bh[j][ks], acc[i][j], 0, 0, 0);
    __syncthreads();
  }
#pragma unroll
  for (int i = 0; i < 4; ++i)
#pragma unroll
    for (int j = 0; j < 4; ++j) {
      int e = m0 + wm * 64 + i * 16 + lg * 4;
      int d = n0 + wn * 64 + j * 16 + lr;
      f16x4 vh;
#pragma unroll
      for (int r = 0; r < 4; ++r) vh[r] = (_Float16)(acc[i][j][r] * invdeg[e + r]);
      *(f16x4*)&e1[((size_t)b * DD + d) * EE + e] = vh;
    }
}

// out1[b,e,d] = sum_f w2t[e,f]*e1[d,f]; 128e x 64d tile, BK=64; b-pinned XCD, ep innermost
__global__ __launch_bounds__(256) void k_out1(const _Float16* __restrict__ w2t, const _Float16* __restrict__ e1,
                                              float* __restrict__ out1, _Float16* __restrict__ out1T) {
  __shared__ _Float16 smA[128 * 64];
  __shared__ _Float16 smB[64 * 64];
  int bid = blockIdx.x;
  int xcd = bid & 7, il = bid >> 3;            // 192 per XCD
  int ep = il & 7, dblk = (il >> 3) & 3, bl = il >> 5;
  int b = xcd * 6 + bl;
  int m0 = ep * 128;  // e
  int n0 = dblk * 64; // d
  int t = threadIdx.x, w = t >> 6, l = t & 63;
  int wm = w >> 1, wn = w & 1;
  int lr = l & 15, lg = l >> 4;
  int srow = l >> 3, sgrp = l & 7;
  int sc = (sgrp ^ srow) * 8;
  const _Float16* A = w2t + (size_t)m0 * EE;
  const _Float16* Bp = e1 + ((size_t)b * DD + n0) * EE;
  f32x4 acc[4][2];
  f32x4 z = {0.f, 0.f, 0.f, 0.f};
#pragma unroll
  for (int i = 0; i < 4; ++i)
#pragma unroll
    for (int j = 0; j < 2; ++j) acc[i][j] = z;
  for (int kk = 0; kk < EE; kk += 64) {
#pragma unroll
    for (int q = 0; q < 4; ++q) {
      int c = w * 4 + q;
      int r = c * 8 + srow;
      gload16(A + (size_t)r * EE + kk + sc, smA + c * 512);
    }
#pragma unroll
    for (int q = 0; q < 2; ++q) {
      int c = w * 2 + q;
      int r = c * 8 + srow;
      gload16(Bp + (size_t)r * EE + kk + sc, smB + c * 512);
    }
    __syncthreads();
    f16x8 ah[4][2], bh[2][2];
#pragma unroll
    for (int i = 0; i < 4; ++i) {
      int ra = wm * 64 + i * 16 + lr;
#pragma unroll
      for (int ks = 0; ks < 2; ++ks)
        ah[i][ks] = *(const f16x8*)&smA[ra * 64 + (((ks * 4 + lg) ^ (ra & 7)) * 8)];
    }
#pragma unroll
    for (int j = 0; j < 2; ++j) {
      int rb = wn * 32 + j * 16 + lr;
#pragma unroll
      for (int ks = 0; ks < 2; ++ks)
        bh[j][ks] = *(const f16x8*)&smB[rb * 64 + (((ks * 4 + lg) ^ (rb & 7)) * 8)];
    }
#pragma unroll
    for (int ks = 0; ks < 2; ++ks)
#pragma unroll
      for (int i = 0; i < 4; ++i)
#pragma unroll
        for (int j = 0; j < 2; ++j)
          acc[i][j] = __builtin_amdgcn_mfma_f32_16x16x32_f16(ah[i][ks], bh[j][ks], acc[i][j], 0, 0, 0);
    __syncthreads();
  }
#pragma unroll
  for (int i = 0; i < 4; ++i)
#pragma unroll
    for (int j = 0; j < 2; ++j) {
      int e = m0 + wm * 64 + i * 16 + lg * 4;
      int d = n0 + wn * 32 + j * 16 + lr;
      f16x4 v16;
#pragma unroll
      for (int r = 0; r < 4; ++r) {
        out1[((size_t)b * EE + e + r) * DD + d] = acc[i][j][r];
        v16[r] = (_Float16)acc[i][j][r];
      }
      *(f16x4*)&out1T[((size_t)b * DD + d) * EE + e] = v16;
    }
}

// att16[b,n,e] = softmax coefficient (fp16)
__global__ __launch_bounds__(256) void k_att(const float* __restrict__ inc, const float* __restrict__ node_sc,
                                             const float* __restrict__ edge_sc, const float* __restrict__ time_e,
                                             const float* __restrict__ rmax, const float* __restrict__ rinv,
                                             const float* __restrict__ a3, _Float16* __restrict__ att16) {
  int n = blockIdx.x, b = blockIdx.y;
  int e = threadIdx.x * 4;
  float a30 = a3[0], a31 = a3[1];
  float ns = node_sc[b * NN + n];
  float4 icv = *(const float4*)&inc[(size_t)n * EE + e];
  int be = b * EE + e;
  float4 esc = *(const float4*)&edge_sc[be];
  float4 te = *(const float4*)&time_e[be];
  float4 rm = *(const float4*)&rmax[be];
  float4 ri = *(const float4*)&rinv[be];
  float ica[4] = {icv.x, icv.y, icv.z, icv.w};
  float ea[4] = {esc.x, esc.y, esc.z, esc.w};
  float ta[4] = {te.x, te.y, te.z, te.w};
  float ma[4] = {rm.x, rm.y, rm.z, rm.w};
  float ra[4] = {ri.x, ri.y, ri.z, ri.w};
  f16x4 o;
#pragma unroll
  for (int q = 0; q < 4; ++q) {
    float att = 0.f;
    if (ica[q] > 0.f) {
      float s1 = lrelu(ns + ea[q]);
      float s2 = lrelu(ta[q] * a30 + s1 * a31);
      att = __expf(s2 - ma[q]) * ra[q];
    }
    o[q] = (_Float16)att;
  }
  *(f16x4*)&att16[((size_t)b * NN + n) * EE + e] = o;
}

// out0[b,d,n] = sum_e att16[n,e]*out1T16[d,e]; fp16 MFMA, swizzled LDS; b-pinned XCD
__global__ __launch_bounds__(256) void k_fgemm(const _Float16* __restrict__ att16, const _Float16* __restrict__ out1T,
                                               float* __restrict__ out0) {
  __shared__ _Float16 smA[64 * 64];
  __shared__ _Float16 smB[64 * 64];
  int bid = blockIdx.x;
  int xcd = bid & 7, il = bid >> 3;           // 96 per XCD
  int ntile = il & 3, dtile = (il >> 2) & 3, bl = il >> 4;
  int b = xcd * 6 + bl;
  int n0 = ntile * 64, d0 = dtile * 64;
  int t = threadIdx.x, w = t >> 6, l = t & 63;
  int wm = w >> 1, wn = w & 1;
  int lr = l & 15;
  const _Float16* A = att16 + ((size_t)b * NN + n0) * EE;
  const _Float16* Bp = out1T + ((size_t)b * DD + d0) * EE;
  int lrow = l >> 3;
  int scol = 8 * ((l & 7) ^ (lrow & 7));
  f32x4 acc[2][2];
  f32x4 z = {0.f, 0.f, 0.f, 0.f};
#pragma unroll
  for (int i = 0; i < 2; ++i)
#pragma unroll
    for (int j = 0; j < 2; ++j) acc[i][j] = z;
  for (int kk = 0; kk < EE; kk += 64) {
#pragma unroll
    for (int q = 0; q < 2; ++q) {
      int row = q * 32 + w * 8 + lrow;
      int lb = (q * 32 + w * 8) * 64;
      gload16(A + (size_t)row * EE + kk + scol, smA + lb);
      gload16(Bp + (size_t)row * EE + kk + scol, smB + lb);
    }
    __syncthreads();
    f16x8 af[2][2], bf[2][2];
#pragma unroll
    for (int i = 0; i < 2; ++i)
#pragma unroll
      for (int ks = 0; ks < 2; ++ks) {
        int ra = wm * 32 + i * 16 + lr;
        af[i][ks] = *(const f16x8*)&smA[ra * 64 + ((ks * 32 + (l >> 4) * 8) ^ ((ra & 7) << 3))];
        int rb = wn * 32 + i * 16 + lr;
        bf[i][ks] = *(const f16x8*)&smB[rb * 64 + ((ks * 32 + (l >> 4) * 8) ^ ((rb & 7) << 3))];
      }
#pragma unroll
    for (int ks = 0; ks < 2; ++ks)
#pragma unroll
      for (int i = 0; i < 2; ++i)
#pragma unroll
        for (int j = 0; j < 2; ++j)
          acc[i][j] = __builtin_amdgcn_mfma_f32_16x16x32_f16(af[i][ks], bf[j][ks], acc[i][j], 0, 0, 0);
    __syncthreads();
  }
  float* ob = out0 + (size_t)b * DD * NN;
#pragma unroll
  for (int i = 0; i < 2; ++i)
#pragma unroll
    for (int j = 0; j < 2; ++j) {
      int n = n0 + wm * 32 + i * 16 + (l >> 4) * 4;
      int d = d0 + wn * 32 + j * 16 + lr;
      *(float4*)&ob[(size_t)d * NN + n] =
          make_float4(acc[i][j][0], acc[i][j][1], acc[i][j][2], acc[i][j][3]);
    }
}

extern "C" void kernel_launch(void* const* d_in, const int* in_sizes, int n_in, void* d_out, int out_size,
                              void* d_ws, size_t ws_size, hipStream_t stream) {
  (void)in_sizes;
  (void)n_in;
  (void)out_size;
  (void)ws_size;
  const float* x = (const float*)d_in[0];
  const float* m = (const float*)d_in[1];
  const float* hid = (const float*)d_in[2];
  const float* pri_e = (const float*)d_in[3];
  const float* inc = (const float*)d_in[5];
  const float* W = (const float*)d_in[6];
  const float* bias = (const float*)d_in[7];
  const float* W2 = (const float*)d_in[8];
  const float* a = (const float*)d_in[9];
  const float* a2 = (const float*)d_in[10];
  const float* a3 = (const float*)d_in[11];

  float* out0 = (float*)d_out;                // [B,D,N]
  float* out1 = out0 + (size_t)BB * DD * NN;  // [B,E,D] fp32
  _Float16* hThi = (_Float16*)out1;           // [B,D,N] fp16 (dead before k_out1 writes out1)

  _Float16* e1 = (_Float16*)d_ws;  // [B,D,E] fp16; att16 aliases after k_out1
  _Float16* att16 = e1;
  _Float16* out1T16 = e1 + (size_t)BB * DD * EE;      // [B,D,E] fp16
  _Float16* incT = out1T16 + (size_t)BB * DD * EE;    // [E,N]
  _Float16* w2thi = incT + (size_t)EE * NN;           // [E,E]
  float* invdeg = (float*)(w2thi + (size_t)EE * EE);  // E
  float* node_sc = invdeg + EE;                       // B*N
  float* g1 = node_sc + (size_t)BB * NN;              // B*N
  float* g2 = g1 + (size_t)BB * NN;                   // B*N
  float* edge_sc = g2 + (size_t)BB * NN;              // B*E
  float* time_e = edge_sc + (size_t)BB * EE;          // B*E
  float* rmax = time_e + (size_t)BB * EE;             // B*E
  float* rinv = rmax + (size_t)BB * EE;               // B*E
  float* u1 = rinv + (size_t)BB * EE;                 // B*E
  float* u2 = u1 + (size_t)BB * EE;                   // B*E
  float* part = u2 + (size_t)BB * EE;                 // 4*B*N*3

  k_deg<<<dim3(EE / 256), 256, 0, stream>>>(inc, invdeg);
  k_incT<<<dim3(EE / 64, NN / 64), 256, 0, stream>>>(inc, incT);
  k_w2t<<<dim3(EE / 64, EE / 64), 256, 0, stream>>>(W2, w2thi);
  k_h<<<dim3(DD / 64, NN / 64, BB), 256, 0, stream>>>(x, m, hid, W, bias, a, a2, hThi, part);
  k_nred<<<dim3((BB * NN) / 256), 256, 0, stream>>>(part, node_sc, g1, g2);
  k_uu<<<dim3(EE / 64, BB), 256, 0, stream>>>(incT, g1, g2, invdeg, u1, u2);
  k_esc<<<dim3(EE / 64, BB / 6), 256, 0, stream>>>(W2, u1, u2, pri_e, a2, edge_sc, time_e);
  k_d3<<<dim3((BB * EE) / 4), 256, 0, stream>>>(incT, node_sc, edge_sc, time_e, a3, rmax, rinv);
  k_edge1<<<dim3(8 * 96), 256, 0, stream>>>(incT, hThi, invdeg, e1);
  k_out1<<<dim3(8 * 192), 256, 0, stream>>>(w2thi, e1, out1, out1T16);
  k_att<<<dim3(NN, BB), 256, 0, stream>>>(inc, node_sc, edge_sc, time_e, rmax, rinv, a3, att16);
  k_fgemm<<<dim3(8 * 96), 256, 0, stream>>>(att16, out1T16, out0);
}

// Round 7
// 185.654 us; speedup vs baseline: 3.4608x; 1.0306x over previous
//
#include <hip/hip_runtime.h>

#define BB 48
#define NN 256
#define EE 1024
#define DD 256
#define CIN 256

typedef __attribute__((ext_vector_type(4))) float f32x4;
typedef __attribute__((ext_vector_type(8))) _Float16 f16x8;
typedef __attribute__((ext_vector_type(4))) _Float16 f16x4;

__device__ __forceinline__ float lrelu(float t) { return t >= 0.0f ? t : 0.2f * t; }

__device__ __forceinline__ void gload16(const void* g, void* l) {
  __builtin_amdgcn_global_load_lds((const __attribute__((address_space(1))) void*)g,
                                   (__attribute__((address_space(3))) void*)l, 16, 0, 0);
}

// deg[e] = sum_n inc[n,e]; store 1/deg
__global__ __launch_bounds__(256) void k_deg(const float* __restrict__ inc, float* __restrict__ invdeg) {
  int e = blockIdx.x * 256 + threadIdx.x;
  float s = 0.f;
  for (int n = 0; n < NN; ++n) s += inc[(size_t)n * EE + e];
  invdeg[e] = 1.0f / s;
}

// incT[e,n] = inc[n,e]  (fp16, exact 0/1)
__global__ __launch_bounds__(256) void k_incT(const float* __restrict__ inc, _Float16* __restrict__ incT) {
  __shared__ float tile[64][65];
  int e0 = blockIdx.x * 64, n0 = blockIdx.y * 64;
  int t = threadIdx.x, c = t & 63, r = t >> 6;
#pragma unroll
  for (int i = 0; i < 16; ++i) tile[r + i * 4][c] = inc[(size_t)(n0 + r + i * 4) * EE + e0 + c];
  __syncthreads();
#pragma unroll
  for (int i = 0; i < 16; ++i) {
    int row = r + i * 4;
    incT[(size_t)(e0 + row) * NN + n0 + c] = (_Float16)tile[c][row];
  }
}

// w2t[e,f] = fp16(W2[f,e])
__global__ __launch_bounds__(256) void k_w2t(const float* __restrict__ W2, _Float16* __restrict__ hi) {
  __shared__ float tile[64][65];
  int f0 = blockIdx.x * 64, e0 = blockIdx.y * 64;
  int t = threadIdx.x, c = t & 63, r = t >> 6;
#pragma unroll
  for (int i = 0; i < 16; ++i) tile[r + i * 4][c] = W2[(size_t)(f0 + r + i * 4) * EE + e0 + c];
  __syncthreads();
#pragma unroll
  for (int i = 0; i < 16; ++i) {
    int row = r + i * 4;
    hi[(size_t)(e0 + row) * EE + f0 + c] = (_Float16)tile[c][row];
  }
}

// wt16[d,c] = fp16(W[c,d])
__global__ __launch_bounds__(256) void k_wt16(const float* __restrict__ W, _Float16* __restrict__ wt) {
  __shared__ float tile[64][65];
  int c0 = blockIdx.x * 64, d0 = blockIdx.y * 64;
  int t = threadIdx.x, c = t & 63, r = t >> 6;
#pragma unroll
  for (int i = 0; i < 16; ++i) tile[r + i * 4][c] = W[(size_t)(c0 + r + i * 4) * DD + d0 + c];
  __syncthreads();
#pragma unroll
  for (int i = 0; i < 16; ++i) {
    int row = r + i * 4;
    wt[(size_t)(d0 + row) * CIN + c0 + c] = (_Float16)tile[c][row];
  }
}

// xt16[b,n,c] = fp16(x_in[b,c,n])
__global__ __launch_bounds__(256) void k_xt(const float* __restrict__ x, const float* __restrict__ m,
                                            const float* __restrict__ hid, _Float16* __restrict__ xt) {
  __shared__ float tile[64][65];
  int c0 = blockIdx.x * 64, n0 = blockIdx.y * 64, b = blockIdx.z;
  int t = threadIdx.x, c = t & 63, r = t >> 6;
#pragma unroll
  for (int i = 0; i < 16; ++i) {
    int ch = c0 + r + i * 4;
    const float* row;
    if (ch < 96) row = x + ((size_t)b * 96 + ch) * NN;
    else if (ch < 192) row = m + ((size_t)b * 96 + (ch - 96)) * NN;
    else row = hid + ((size_t)b * 64 + (ch - 192)) * NN;
    tile[r + i * 4][c] = row[n0 + c];
  }
  __syncthreads();
#pragma unroll
  for (int i = 0; i < 16; ++i) {
    int row = r + i * 4;
    xt[((size_t)b * NN + n0 + row) * CIN + c0 + c] = (_Float16)tile[c][row];
  }
}

// wa[c]=sum_d W[c,d]*a[d]; wa[256+c]=..a[D+d]; wa[512+c]=..a2[d]; wa[768..770]=sum(a[:D]),sum(a[D:]),sum(a2[:D])
__global__ __launch_bounds__(256) void k_wa(const float* __restrict__ W, const float* __restrict__ a,
                                            const float* __restrict__ a2, float* __restrict__ wa) {
  __shared__ float red[3][4];
  int c = blockIdx.x, t = threadIdx.x;
  int l = t & 63, wv = t >> 6;
  float w = W[(size_t)c * DD + t];
  float p0 = w * a[t], p1 = w * a[DD + t], p2 = w * a2[t];
#pragma unroll
  for (int off = 32; off > 0; off >>= 1) {
    p0 += __shfl_down(p0, off);
    p1 += __shfl_down(p1, off);
    p2 += __shfl_down(p2, off);
  }
  if (l == 0) {
    red[0][wv] = p0;
    red[1][wv] = p1;
    red[2][wv] = p2;
  }
  __syncthreads();
  if (t == 0) wa[c] = red[0][0] + red[0][1] + red[0][2] + red[0][3];
  if (t == 1) wa[256 + c] = red[1][0] + red[1][1] + red[1][2] + red[1][3];
  if (t == 2) wa[512 + c] = red[2][0] + red[2][1] + red[2][2] + red[2][3];
  if (blockIdx.x == 0) {
    __syncthreads();
    float q0 = a[t], q1 = a[DD + t], q2 = a2[t];
#pragma unroll
    for (int off = 32; off > 0; off >>= 1) {
      q0 += __shfl_down(q0, off);
      q1 += __shfl_down(q1, off);
      q2 += __shfl_down(q2, off);
    }
    if (l == 0) {
      red[0][wv] = q0;
      red[1][wv] = q1;
      red[2][wv] = q2;
    }
    __syncthreads();
    if (t == 0) wa[768] = red[0][0] + red[0][1] + red[0][2] + red[0][3];
    if (t == 1) wa[769] = red[1][0] + red[1][1] + red[1][2] + red[1][3];
    if (t == 2) wa[770] = red[2][0] + red[2][1] + red[2][2] + red[2][3];
  }
}

// per-(b, c-quarter) partial score dots from x_in directly (exact fp32)
__global__ __launch_bounds__(256) void k_ns(const float* __restrict__ x, const float* __restrict__ m,
                                            const float* __restrict__ hid, const float* __restrict__ wa,
                                            float* __restrict__ part) {
  __shared__ float s0a[64], s1a[64], s2a[64];
  int q = blockIdx.x, b = blockIdx.y;
  int t = threadIdx.x;
  if (t < 64) s0a[t] = wa[q * 64 + t];
  else if (t < 128) s1a[t - 64] = wa[256 + q * 64 + (t - 64)];
  else if (t < 192) s2a[t - 128] = wa[512 + q * 64 + (t - 128)];
  __syncthreads();
  float s0 = 0.f, s1 = 0.f, s2 = 0.f;
  for (int i = 0; i < 64; ++i) {
    int ch = q * 64 + i;
    const float* row;
    if (ch < 96) row = x + ((size_t)b * 96 + ch) * NN;
    else if (ch < 192) row = m + ((size_t)b * 96 + (ch - 96)) * NN;
    else row = hid + ((size_t)b * 64 + (ch - 192)) * NN;
    float v = row[t];
    s0 += v * s0a[i];
    s1 += v * s1a[i];
    s2 += v * s2a[i];
  }
  size_t pb = ((size_t)(q * BB + b) * NN + t) * 3;
  part[pb] = s0;
  part[pb + 1] = s1;
  part[pb + 2] = s2;
}

// reduce 4 c-quarter partials + bias terms -> node_sc, g1, g2
__global__ __launch_bounds__(256) void k_nred(const float* __restrict__ part, const float* __restrict__ bias,
                                              const float* __restrict__ wa, float* __restrict__ node_sc,
                                              float* __restrict__ g1, float* __restrict__ g2) {
  int idx = blockIdx.x * 256 + threadIdx.x;  // b*N+n
  int n = idx & (NN - 1);
  float s0 = 0.f, s1 = 0.f, s2 = 0.f;
#pragma unroll
  for (int q = 0; q < 4; ++q) {
    size_t pb = ((size_t)q * BB * NN + idx) * 3;
    s0 += part[pb];
    s1 += part[pb + 1];
    s2 += part[pb + 2];
  }
  float bv = bias[n];
  node_sc[idx] = s0 + bv * wa[768];
  g1[idx] = s1 + bv * wa[769];
  g2[idx] = s2 + bv * wa[770];
}

// hThi[b,d,n] = fp16( sum_c xt16[b,n,c]*wt16[d,c] + bias[n] ); fp16 MFMA, 64x64 tiles
__global__ __launch_bounds__(256) void k_h16(const _Float16* __restrict__ xt, const _Float16* __restrict__ wt,
                                             const float* __restrict__ bias, _Float16* __restrict__ hThi) {
  __shared__ _Float16 smA[64 * 64];
  __shared__ _Float16 smB[64 * 64];
  int bid = blockIdx.x;
  int xcd = bid & 7, il = bid >> 3;  // 96 per XCD
  int ntile = il & 3, dtile = (il >> 2) & 3, bl = il >> 4;
  int b = xcd * 6 + bl;
  int n0 = ntile * 64, d0 = dtile * 64;
  int t = threadIdx.x, w = t >> 6, l = t & 63;
  int wm = w >> 1, wn = w & 1;
  int lr = l & 15;
  const _Float16* A = xt + ((size_t)b * NN + n0) * CIN;
  const _Float16* Bp = wt + (size_t)d0 * CIN;
  int lrow = l >> 3;
  int scol = 8 * ((l & 7) ^ (lrow & 7));
  f32x4 acc[2][2];
  f32x4 z = {0.f, 0.f, 0.f, 0.f};
#pragma unroll
  for (int i = 0; i < 2; ++i)
#pragma unroll
    for (int j = 0; j < 2; ++j) acc[i][j] = z;
  for (int kk = 0; kk < CIN; kk += 64) {
#pragma unroll
    for (int q = 0; q < 2; ++q) {
      int row = q * 32 + w * 8 + lrow;
      int lb = (q * 32 + w * 8) * 64;
      gload16(A + (size_t)row * CIN + kk + scol, smA + lb);
      gload16(Bp + (size_t)row * CIN + kk + scol, smB + lb);
    }
    __syncthreads();
    f16x8 af[2][2], bf[2][2];
#pragma unroll
    for (int i = 0; i < 2; ++i)
#pragma unroll
      for (int ks = 0; ks < 2; ++ks) {
        int ra = wm * 32 + i * 16 + lr;
        af[i][ks] = *(const f16x8*)&smA[ra * 64 + ((ks * 32 + (l >> 4) * 8) ^ ((ra & 7) << 3))];
        int rb = wn * 32 + i * 16 + lr;
        bf[i][ks] = *(const f16x8*)&smB[rb * 64 + ((ks * 32 + (l >> 4) * 8) ^ ((rb & 7) << 3))];
      }
#pragma unroll
    for (int ks = 0; ks < 2; ++ks)
#pragma unroll
      for (int i = 0; i < 2; ++i)
#pragma unroll
        for (int j = 0; j < 2; ++j)
          acc[i][j] = __builtin_amdgcn_mfma_f32_16x16x32_f16(af[i][ks], bf[j][ks], acc[i][j], 0, 0, 0);
    __syncthreads();
  }
#pragma unroll
  for (int i = 0; i < 2; ++i)
#pragma unroll
    for (int j = 0; j < 2; ++j) {
      int nb = n0 + wm * 32 + i * 16 + (l >> 4) * 4;
      int d = d0 + wn * 32 + j * 16 + lr;
      float4 bv = *(const float4*)&bias[nb];
      f16x4 vh;
      vh[0] = (_Float16)(acc[i][j][0] + bv.x);
      vh[1] = (_Float16)(acc[i][j][1] + bv.y);
      vh[2] = (_Float16)(acc[i][j][2] + bv.z);
      vh[3] = (_Float16)(acc[i][j][3] + bv.w);
      *(f16x4*)&hThi[((size_t)b * DD + d) * NN + nb] = vh;
    }
}

// u1[b,f] = invdeg[f]*sum_n incT[f,n]*g1[b,n];  u2 same with g2   (exact fp32)
__global__ __launch_bounds__(256) void k_uu(const _Float16* __restrict__ incT, const float* __restrict__ g1,
                                            const float* __restrict__ g2, const float* __restrict__ invdeg,
                                            float* __restrict__ u1, float* __restrict__ u2) {
  __shared__ float sg1[NN], sg2[NN];
  __shared__ float r1[4][64], r2[4][64];
  int b = blockIdx.y;
  int f0 = blockIdx.x * 64;
  int t = threadIdx.x;
  sg1[t] = g1[b * NN + t];
  sg2[t] = g2[b * NN + t];
  __syncthreads();
  int fl = t & 63, ng = t >> 6;
  int f = f0 + fl;
  float s1 = 0.f, s2 = 0.f;
  const _Float16* row = incT + (size_t)f * NN + ng * 64;
  for (int i = 0; i < 64; i += 8) {
    f16x8 ic = *(const f16x8*)&row[i];
#pragma unroll
    for (int j = 0; j < 8; ++j) {
      float icf = (float)ic[j];
      int n = ng * 64 + i + j;
      s1 += icf * sg1[n];
      s2 += icf * sg2[n];
    }
  }
  r1[ng][fl] = s1;
  r2[ng][fl] = s2;
  __syncthreads();
  if (t < 64) {
    float iv = invdeg[f0 + t];
    u1[(size_t)b * EE + f0 + t] = (r1[0][t] + r1[1][t] + r1[2][t] + r1[3][t]) * iv;
    u2[(size_t)b * EE + f0 + t] = (r2[0][t] + r2[1][t] + r2[2][t] + r2[3][t]) * iv;
  }
}

// edge_sc[b,e] = sum_f W2[f,e]*u1[b,f];  time_e = lrelu(... + pri_e*a2[D]); 6 b per block
__global__ __launch_bounds__(256) void k_esc(const float* __restrict__ W2, const float* __restrict__ u1,
                                             const float* __restrict__ u2, const float* __restrict__ pri_e,
                                             const float* __restrict__ a2, float* __restrict__ edge_sc,
                                             float* __restrict__ time_e) {
  __shared__ float su1[6 * 1024];
  __shared__ float su2[6 * 1024];
  __shared__ float rr[2][4][6][64];
  int e0 = blockIdx.x * 64, b0 = blockIdx.y * 6;
  int t = threadIdx.x;
#pragma unroll
  for (int i = 0; i < 6; ++i) {
    *(float4*)&su1[i * 1024 + t * 4] = *(const float4*)&u1[(size_t)(b0 + i) * EE + t * 4];
    *(float4*)&su2[i * 1024 + t * 4] = *(const float4*)&u2[(size_t)(b0 + i) * EE + t * 4];
  }
  __syncthreads();
  int el = t & 63, fg = t >> 6;
  int e = e0 + el;
  float s1[6] = {}, s2[6] = {};
  for (int i = 0; i < 256; i += 4) {
    int f = fg * 256 + i;
    float w0 = W2[(size_t)f * EE + e];
    float w1 = W2[(size_t)(f + 1) * EE + e];
    float w2v = W2[(size_t)(f + 2) * EE + e];
    float w3 = W2[(size_t)(f + 3) * EE + e];
#pragma unroll
    for (int bl = 0; bl < 6; ++bl) {
      f32x4 va = *(const f32x4*)&su1[bl * 1024 + f];
      f32x4 vb = *(const f32x4*)&su2[bl * 1024 + f];
      s1[bl] += w0 * va[0] + w1 * va[1] + w2v * va[2] + w3 * va[3];
      s2[bl] += w0 * vb[0] + w1 * vb[1] + w2v * vb[2] + w3 * vb[3];
    }
  }
#pragma unroll
  for (int bl = 0; bl < 6; ++bl) {
    rr[0][fg][bl][el] = s1[bl];
    rr[1][fg][bl][el] = s2[bl];
  }
  __syncthreads();
  for (int bl = t >> 6; bl < 6; bl += 4) {
    int ee = t & 63;
    int row = (b0 + bl) * EE + e0 + ee;
    float v1 = rr[0][0][bl][ee] + rr[0][1][bl][ee] + rr[0][2][bl][ee] + rr[0][3][bl][ee];
    float v2 = rr[1][0][bl][ee] + rr[1][1][bl][ee] + rr[1][2][bl][ee] + rr[1][3][bl][ee];
    edge_sc[row] = v1;
    time_e[row] = lrelu(v2 + pri_e[row] * a2[DD]);
  }
}

// softmax stats over n per (b,e)
__global__ __launch_bounds__(256) void k_d3(const _Float16* __restrict__ incT, const float* __restrict__ node_sc,
                                            const float* __restrict__ edge_sc, const float* __restrict__ time_e,
                                            const float* __restrict__ a3, float* __restrict__ rmax,
                                            float* __restrict__ rinv) {
  int t = threadIdx.x;
  int w = t >> 6, l = t & 63;
  int row = blockIdx.x * 4 + w;
  int b = row >> 10;
  int e = row & (EE - 1);
  float a30 = a3[0], a31 = a3[1];
  float esc = edge_sc[row], te = time_e[row];
  float s2v[4];
  bool msk[4];
  float vmax = -3.0e38f;
#pragma unroll
  for (int q = 0; q < 4; ++q) {
    int n = l + q * 64;
    float ic = (float)incT[(size_t)e * NN + n];
    float s1 = lrelu(node_sc[(size_t)b * NN + n] + esc);
    float s2 = lrelu(te * a30 + s1 * a31);
    msk[q] = ic > 0.f;
    s2v[q] = s2;
    if (msk[q]) vmax = fmaxf(vmax, s2);
  }
#pragma unroll
  for (int off = 32; off > 0; off >>= 1) vmax = fmaxf(vmax, __shfl_xor(vmax, off));
  float ss = 0.f;
#pragma unroll
  for (int q = 0; q < 4; ++q)
    if (msk[q]) ss += __expf(s2v[q] - vmax);
#pragma unroll
  for (int off = 32; off > 0; off >>= 1) ss += __shfl_xor(ss, off);
  if (l == 0) {
    rmax[row] = vmax;
    rinv[row] = 1.0f / ss;
  }
}

// e1[b,d,e] = (sum_n hT[d,n]*incT[e,n]) * invdeg[e]; 1-term MFMA, BK=64, XOR swizzle; b-pinned XCD
__global__ __launch_bounds__(256) void k_edge1(const _Float16* __restrict__ incT, const _Float16* __restrict__ hThi,
                                               const float* __restrict__ invdeg, _Float16* __restrict__ e1) {
  __shared__ _Float16 smA[128 * 64];
  __shared__ _Float16 smB[128 * 64];
  int bid = blockIdx.x;
  int xcd = bid & 7, il = bid >> 3;  // 96 per XCD
  int ep = il & 7, dblk = (il >> 3) & 1, bl = il >> 4;
  int b = xcd * 6 + bl;
  int m0 = ep * 128;    // e
  int n0 = dblk * 128;  // d
  int t = threadIdx.x, w = t >> 6, l = t & 63;
  int wm = w >> 1, wn = w & 1;
  int lr = l & 15, lg = l >> 4;
  int srow = l >> 3, sgrp = l & 7;
  int sc = (sgrp ^ srow) * 8;
  const _Float16* A = incT + (size_t)m0 * NN;
  const _Float16* Bp = hThi + ((size_t)b * DD + n0) * NN;
  f32x4 acc[4][4];
  f32x4 z = {0.f, 0.f, 0.f, 0.f};
#pragma unroll
  for (int i = 0; i < 4; ++i)
#pragma unroll
    for (int j = 0; j < 4; ++j) acc[i][j] = z;
  for (int kk = 0; kk < NN; kk += 64) {
#pragma unroll
    for (int q = 0; q < 4; ++q) {
      int c = w * 4 + q;
      int r = c * 8 + srow;
      gload16(A + (size_t)r * NN + kk + sc, smA + c * 512);
      gload16(Bp + (size_t)r * NN + kk + sc, smB + c * 512);
    }
    __syncthreads();
    f16x8 ah[4][2], bh[4][2];
#pragma unroll
    for (int i = 0; i < 4; ++i) {
      int ra = wm * 64 + i * 16 + lr;
      int rb = wn * 64 + i * 16 + lr;
#pragma unroll
      for (int ks = 0; ks < 2; ++ks) {
        ah[i][ks] = *(const f16x8*)&smA[ra * 64 + (((ks * 4 + lg) ^ (ra & 7)) * 8)];
        bh[i][ks] = *(const f16x8*)&smB[rb * 64 + (((ks * 4 + lg) ^ (rb & 7)) * 8)];
      }
    }
#pragma unroll
    for (int ks = 0; ks < 2; ++ks)
#pragma unroll
      for (int i = 0; i < 4; ++i)
#pragma unroll
        for (int j = 0; j < 4; ++j)
          acc[i][j] = __builtin_amdgcn_mfma_f32_16x16x32_f16(ah[i][ks], bh[j][ks], acc[i][j], 0, 0, 0);
    __syncthreads();
  }
#pragma unroll
  for (int i = 0; i < 4; ++i)
#pragma unroll
    for (int j = 0; j < 4; ++j) {
      int e = m0 + wm * 64 + i * 16 + lg * 4;
      int d = n0 + wn * 64 + j * 16 + lr;
      f16x4 vh;
#pragma unroll
      for (int r = 0; r < 4; ++r) vh[r] = (_Float16)(acc[i][j][r] * invdeg[e + r]);
      *(f16x4*)&e1[((size_t)b * DD + d) * EE + e] = vh;
    }
}

// out1[b,e,d] = sum_f w2t[e,f]*e1[d,f]; 128e x 64d tile, BK=64; b-pinned XCD, ep innermost
__global__ __launch_bounds__(256) void k_out1(const _Float16* __restrict__ w2t, const _Float16* __restrict__ e1,
                                              float* __restrict__ out1, _Float16* __restrict__ out1T) {
  __shared__ _Float16 smA[128 * 64];
  __shared__ _Float16 smB[64 * 64];
  int bid = blockIdx.x;
  int xcd = bid & 7, il = bid >> 3;  // 192 per XCD
  int ep = il & 7, dblk = (il >> 3) & 3, bl = il >> 5;
  int b = xcd * 6 + bl;
  int m0 = ep * 128;   // e
  int n0 = dblk * 64;  // d
  int t = threadIdx.x, w = t >> 6, l = t & 63;
  int wm = w >> 1, wn = w & 1;
  int lr = l & 15, lg = l >> 4;
  int srow = l >> 3, sgrp = l & 7;
  int sc = (sgrp ^ srow) * 8;
  const _Float16* A = w2t + (size_t)m0 * EE;
  const _Float16* Bp = e1 + ((size_t)b * DD + n0) * EE;
  f32x4 acc[4][2];
  f32x4 z = {0.f, 0.f, 0.f, 0.f};
#pragma unroll
  for (int i = 0; i < 4; ++i)
#pragma unroll
    for (int j = 0; j < 2; ++j) acc[i][j] = z;
  for (int kk = 0; kk < EE; kk += 64) {
#pragma unroll
    for (int q = 0; q < 4; ++q) {
      int c = w * 4 + q;
      int r = c * 8 + srow;
      gload16(A + (size_t)r * EE + kk + sc, smA + c * 512);
    }
#pragma unroll
    for (int q = 0; q < 2; ++q) {
      int c = w * 2 + q;
      int r = c * 8 + srow;
      gload16(Bp + (size_t)r * EE + kk + sc, smB + c * 512);
    }
    __syncthreads();
    f16x8 ah[4][2], bh[2][2];
#pragma unroll
    for (int i = 0; i < 4; ++i) {
      int ra = wm * 64 + i * 16 + lr;
#pragma unroll
      for (int ks = 0; ks < 2; ++ks)
        ah[i][ks] = *(const f16x8*)&smA[ra * 64 + (((ks * 4 + lg) ^ (ra & 7)) * 8)];
    }
#pragma unroll
    for (int j = 0; j < 2; ++j) {
      int rb = wn * 32 + j * 16 + lr;
#pragma unroll
      for (int ks = 0; ks < 2; ++ks)
        bh[j][ks] = *(const f16x8*)&smB[rb * 64 + (((ks * 4 + lg) ^ (rb & 7)) * 8)];
    }
#pragma unroll
    for (int ks = 0; ks < 2; ++ks)
#pragma unroll
      for (int i = 0; i < 4; ++i)
#pragma unroll
        for (int j = 0; j < 2; ++j)
          acc[i][j] = __builtin_amdgcn_mfma_f32_16x16x32_f16(ah[i][ks], bh[j][ks], acc[i][j], 0, 0, 0);
    __syncthreads();
  }
#pragma unroll
  for (int i = 0; i < 4; ++i)
#pragma unroll
    for (int j = 0; j < 2; ++j) {
      int e = m0 + wm * 64 + i * 16 + lg * 4;
      int d = n0 + wn * 32 + j * 16 + lr;
      f16x4 v16;
#pragma unroll
      for (int r = 0; r < 4; ++r) {
        out1[((size_t)b * EE + e + r) * DD + d] = acc[i][j][r];
        v16[r] = (_Float16)acc[i][j][r];
      }
      *(f16x4*)&out1T[((size_t)b * DD + d) * EE + e] = v16;
    }
}

// att16[b,n,e] = softmax coefficient (fp16)
__global__ __launch_bounds__(256) void k_att(const float* __restrict__ inc, const float* __restrict__ node_sc,
                                             const float* __restrict__ edge_sc, const float* __restrict__ time_e,
                                             const float* __restrict__ rmax, const float* __restrict__ rinv,
                                             const float* __restrict__ a3, _Float16* __restrict__ att16) {
  int n = blockIdx.x, b = blockIdx.y;
  int e = threadIdx.x * 4;
  float a30 = a3[0], a31 = a3[1];
  float ns = node_sc[b * NN + n];
  float4 icv = *(const float4*)&inc[(size_t)n * EE + e];
  int be = b * EE + e;
  float4 esc = *(const float4*)&edge_sc[be];
  float4 te = *(const float4*)&time_e[be];
  float4 rm = *(const float4*)&rmax[be];
  float4 ri = *(const float4*)&rinv[be];
  float ica[4] = {icv.x, icv.y, icv.z, icv.w};
  float ea[4] = {esc.x, esc.y, esc.z, esc.w};
  float ta[4] = {te.x, te.y, te.z, te.w};
  float ma[4] = {rm.x, rm.y, rm.z, rm.w};
  float ra[4] = {ri.x, ri.y, ri.z, ri.w};
  f16x4 o;
#pragma unroll
  for (int q = 0; q < 4; ++q) {
    float att = 0.f;
    if (ica[q] > 0.f) {
      float s1 = lrelu(ns + ea[q]);
      float s2 = lrelu(ta[q] * a30 + s1 * a31);
      att = __expf(s2 - ma[q]) * ra[q];
    }
    o[q] = (_Float16)att;
  }
  *(f16x4*)&att16[((size_t)b * NN + n) * EE + e] = o;
}

// out0[b,d,n] = sum_e att16[n,e]*out1T16[d,e]; fp16 MFMA, swizzled LDS; b-pinned XCD
__global__ __launch_bounds__(256) void k_fgemm(const _Float16* __restrict__ att16, const _Float16* __restrict__ out1T,
                                               float* __restrict__ out0) {
  __shared__ _Float16 smA[64 * 64];
  __shared__ _Float16 smB[64 * 64];
  int bid = blockIdx.x;
  int xcd = bid & 7, il = bid >> 3;  // 96 per XCD
  int ntile = il & 3, dtile = (il >> 2) & 3, bl = il >> 4;
  int b = xcd * 6 + bl;
  int n0 = ntile * 64, d0 = dtile * 64;
  int t = threadIdx.x, w = t >> 6, l = t & 63;
  int wm = w >> 1, wn = w & 1;
  int lr = l & 15;
  const _Float16* A = att16 + ((size_t)b * NN + n0) * EE;
  const _Float16* Bp = out1T + ((size_t)b * DD + d0) * EE;
  int lrow = l >> 3;
  int scol = 8 * ((l & 7) ^ (lrow & 7));
  f32x4 acc[2][2];
  f32x4 z = {0.f, 0.f, 0.f, 0.f};
#pragma unroll
  for (int i = 0; i < 2; ++i)
#pragma unroll
    for (int j = 0; j < 2; ++j) acc[i][j] = z;
  for (int kk = 0; kk < EE; kk += 64) {
#pragma unroll
    for (int q = 0; q < 2; ++q) {
      int row = q * 32 + w * 8 + lrow;
      int lb = (q * 32 + w * 8) * 64;
      gload16(A + (size_t)row * EE + kk + scol, smA + lb);
      gload16(Bp + (size_t)row * EE + kk + scol, smB + lb);
    }
    __syncthreads();
    f16x8 af[2][2], bf[2][2];
#pragma unroll
    for (int i = 0; i < 2; ++i)
#pragma unroll
      for (int ks = 0; ks < 2; ++ks) {
        int ra = wm * 32 + i * 16 + lr;
        af[i][ks] = *(const f16x8*)&smA[ra * 64 + ((ks * 32 + (l >> 4) * 8) ^ ((ra & 7) << 3))];
        int rb = wn * 32 + i * 16 + lr;
        bf[i][ks] = *(const f16x8*)&smB[rb * 64 + ((ks * 32 + (l >> 4) * 8) ^ ((rb & 7) << 3))];
      }
#pragma unroll
    for (int ks = 0; ks < 2; ++ks)
#pragma unroll
      for (int i = 0; i < 2; ++i)
#pragma unroll
        for (int j = 0; j < 2; ++j)
          acc[i][j] = __builtin_amdgcn_mfma_f32_16x16x32_f16(af[i][ks], bf[j][ks], acc[i][j], 0, 0, 0);
    __syncthreads();
  }
  float* ob = out0 + (size_t)b * DD * NN;
#pragma unroll
  for (int i = 0; i < 2; ++i)
#pragma unroll
    for (int j = 0; j < 2; ++j) {
      int n = n0 + wm * 32 + i * 16 + (l >> 4) * 4;
      int d = d0 + wn * 32 + j * 16 + lr;
      *(float4*)&ob[(size_t)d * NN + n] =
          make_float4(acc[i][j][0], acc[i][j][1], acc[i][j][2], acc[i][j][3]);
    }
}

extern "C" void kernel_launch(void* const* d_in, const int* in_sizes, int n_in, void* d_out, int out_size,
                              void* d_ws, size_t ws_size, hipStream_t stream) {
  (void)in_sizes;
  (void)n_in;
  (void)out_size;
  (void)ws_size;
  const float* x = (const float*)d_in[0];
  const float* m = (const float*)d_in[1];
  const float* hid = (const float*)d_in[2];
  const float* pri_e = (const float*)d_in[3];
  const float* inc = (const float*)d_in[5];
  const float* W = (const float*)d_in[6];
  const float* bias = (const float*)d_in[7];
  const float* W2 = (const float*)d_in[8];
  const float* a = (const float*)d_in[9];
  const float* a2 = (const float*)d_in[10];
  const float* a3 = (const float*)d_in[11];

  float* out0 = (float*)d_out;                // [B,D,N]
  float* out1 = out0 + (size_t)BB * DD * NN;  // [B,E,D] fp32
  _Float16* hThi = (_Float16*)out1;           // [B,D,N] fp16 (dead before k_out1 writes out1)
  _Float16* xt16 = hThi + (size_t)BB * DD * NN;  // [B,N,CIN] fp16 (also inside out1 region)

  _Float16* e1 = (_Float16*)d_ws;  // [B,D,E] fp16; att16 aliases after k_out1
  _Float16* att16 = e1;
  _Float16* out1T16 = e1 + (size_t)BB * DD * EE;      // [B,D,E] fp16
  _Float16* incT = out1T16 + (size_t)BB * DD * EE;    // [E,N]
  _Float16* w2thi = incT + (size_t)EE * NN;           // [E,E]
  float* invdeg = (float*)(w2thi + (size_t)EE * EE);  // E
  float* node_sc = invdeg + EE;                       // B*N
  float* g1 = node_sc + (size_t)BB * NN;              // B*N
  float* g2 = g1 + (size_t)BB * NN;                   // B*N
  float* edge_sc = g2 + (size_t)BB * NN;              // B*E
  float* time_e = edge_sc + (size_t)BB * EE;          // B*E
  float* rmax = time_e + (size_t)BB * EE;             // B*E
  float* rinv = rmax + (size_t)BB * EE;               // B*E
  float* u1 = rinv + (size_t)BB * EE;                 // B*E
  float* u2 = u1 + (size_t)BB * EE;                   // B*E
  float* part = u2 + (size_t)BB * EE;                 // 4*B*N*3
  float* wa = part + (size_t)4 * BB * NN * 3;         // 1024
  _Float16* wt16 = (_Float16*)(wa + 1024);            // [D,CIN]

  k_deg<<<dim3(EE / 256), 256, 0, stream>>>(inc, invdeg);
  k_incT<<<dim3(EE / 64, NN / 64), 256, 0, stream>>>(inc, incT);
  k_w2t<<<dim3(EE / 64, EE / 64), 256, 0, stream>>>(W2, w2thi);
  k_wt16<<<dim3(CIN / 64, DD / 64), 256, 0, stream>>>(W, wt16);
  k_xt<<<dim3(CIN / 64, NN / 64, BB), 256, 0, stream>>>(x, m, hid, xt16);
  k_wa<<<dim3(CIN), 256, 0, stream>>>(W, a, a2, wa);
  k_h16<<<dim3(8 * 96), 256, 0, stream>>>(xt16, wt16, bias, hThi);
  k_ns<<<dim3(4, BB), 256, 0, stream>>>(x, m, hid, wa, part);
  k_nred<<<dim3((BB * NN) / 256), 256, 0, stream>>>(part, bias, wa, node_sc, g1, g2);
  k_uu<<<dim3(EE / 64, BB), 256, 0, stream>>>(incT, g1, g2, invdeg, u1, u2);
  k_esc<<<dim3(EE / 64, BB / 6), 256, 0, stream>>>(W2, u1, u2, pri_e, a2, edge_sc, time_e);
  k_d3<<<dim3((BB * EE) / 4), 256, 0, stream>>>(incT, node_sc, edge_sc, time_e, a3, rmax, rinv);
  k_edge1<<<dim3(8 * 96), 256, 0, stream>>>(incT, hThi, invdeg, e1);
  k_out1<<<dim3(8 * 192), 256, 0, stream>>>(w2thi, e1, out1, out1T16);
  k_att<<<dim3(NN, BB), 256, 0, stream>>>(inc, node_sc, edge_sc, time_e, rmax, rinv, a3, att16);
  k_fgemm<<<dim3(8 * 96), 256, 0, stream>>>(att16, out1T16, out0);
}